// Round 1
// baseline (4992.696 us; speedup 1.0000x reference)
//
#include <hip/hip_runtime.h>
#include <math.h>

#define HDIM 64
#define NHEAD 12
#define HDN 768            // H
#define FFDIM 3072
#define LPAST 50
#define SEQ 512
#define NBATCH 16
#define TKV (LPAST + SEQ)  // 562
#define MTOK (NBATCH * SEQ) // 8192

// ---------------------------------------------------------------------------
// Tiled fp32 GEMM: C[M,N] = A[M,K] @ W[K,N] (+ epilogue)
// EPI: 0 = +bias ; 1 = +bias+resid ; 2 = gelu(+bias) ; 3 = accumulate into C
// BM=BN=64, BK=16, 256 threads, 4x4 per thread.
// ---------------------------------------------------------------------------
template<int EPI>
__global__ __launch_bounds__(256) void gemm_f32(
    const float* __restrict__ A, const float* __restrict__ W, int ldw,
    const float* __restrict__ bias, const float* __restrict__ resid,
    float* __restrict__ C, int M, int N, int K)
{
    __shared__ float As[16][68];   // [k][m], stride 68 keeps float4 rows 16B aligned
    __shared__ float Bs[16][68];   // [k][n]

    const int bm = blockIdx.x * 64;
    const int bn = blockIdx.y * 64;
    const int tid = threadIdx.x;
    const int tx = tid & 15;       // n quad
    const int ty = tid >> 4;       // m quad
    const int mA = tid >> 2, kqA = tid & 3;   // A-tile loader mapping
    const int kB = tid >> 4, nqB = tid & 15;  // B-tile loader mapping

    float acc[4][4] = {};

    for (int k0 = 0; k0 < K; k0 += 16) {
        float4 a4 = *(const float4*)&A[(size_t)(bm + mA) * K + k0 + kqA * 4];
        float4 b4 = *(const float4*)&W[(size_t)(k0 + kB) * ldw + bn + nqB * 4];
        As[kqA * 4 + 0][mA] = a4.x;
        As[kqA * 4 + 1][mA] = a4.y;
        As[kqA * 4 + 2][mA] = a4.z;
        As[kqA * 4 + 3][mA] = a4.w;
        *(float4*)&Bs[kB][nqB * 4] = b4;
        __syncthreads();

        #pragma unroll
        for (int kk = 0; kk < 16; ++kk) {
            float4 av = *(const float4*)&As[kk][ty * 4];
            float4 bv = *(const float4*)&Bs[kk][tx * 4];
            float a[4] = {av.x, av.y, av.z, av.w};
            float b[4] = {bv.x, bv.y, bv.z, bv.w};
            #pragma unroll
            for (int i = 0; i < 4; ++i)
                #pragma unroll
                for (int j = 0; j < 4; ++j)
                    acc[i][j] = fmaf(a[i], b[j], acc[i][j]);
        }
        __syncthreads();
    }

    #pragma unroll
    for (int i = 0; i < 4; ++i) {
        const int m = bm + ty * 4 + i;
        #pragma unroll
        for (int j = 0; j < 4; ++j) {
            const int n = bn + tx * 4 + j;
            const size_t idx = (size_t)m * N + n;
            float v = acc[i][j];
            if (EPI == 0) v += bias[n];
            if (EPI == 1) v += bias[n] + resid[idx];
            if (EPI == 2) { v += bias[n]; v = 0.5f * v * (1.0f + erff(v * 0.70710678118654752f)); }
            if (EPI == 3) v += C[idx];
            C[idx] = v;
        }
    }
}

// ---------------------------------------------------------------------------
// Assemble K/V caches: kfull/vfull [B, NH, TKV, HD].
// Faithful to the reference bug: past_key goes into BOTH k and v.
// ---------------------------------------------------------------------------
__global__ __launch_bounds__(256) void kv_assemble(
    const float* __restrict__ kn, const float* __restrict__ vn,
    const float* __restrict__ past_key,
    float* __restrict__ kf, float* __restrict__ vf)
{
    const size_t total = (size_t)NBATCH * NHEAD * TKV * HDIM;
    size_t idx = (size_t)blockIdx.x * 256 + threadIdx.x;
    if (idx >= total) return;
    int d = idx & 63;
    size_t r = idx >> 6;
    int t = (int)(r % TKV); r /= TKV;
    int h = (int)(r % NHEAD);
    int b = (int)(r / NHEAD);
    float kv, vv;
    if (t < LPAST) {
        float pk = past_key[(((size_t)b * NHEAD + h) * LPAST + t) * HDIM + d];
        kv = pk; vv = pk;   // source bug: past_key concatenated into both
    } else {
        int s = t - LPAST;
        size_t off = ((size_t)(b * SEQ + s)) * HDN + h * HDIM + d;
        kv = kn[off]; vv = vn[off];
    }
    kf[idx] = kv; vf[idx] = vv;
}

// ---------------------------------------------------------------------------
// Attention: one wave per (b,h,s) query row; 4 waves per block.
// ctx may alias q (each row's q is read only by its own wave, before the write)
// ---------------------------------------------------------------------------
__global__ __launch_bounds__(256) void attn_kernel(
    const float* q, const float* __restrict__ kf,
    const float* __restrict__ vf, const float* __restrict__ mask,
    float* ctx)
{
    __shared__ float qs[4][64];
    __shared__ float ps[4][TKV];

    const int wave = threadIdx.x >> 6;
    const int lane = threadIdx.x & 63;
    const size_t row = (size_t)blockIdx.x * 4 + wave;   // over B*NH*S
    const int s = (int)(row % SEQ);
    const size_t r = row / SEQ;
    const int h = (int)(r % NHEAD);
    const int b = (int)(r / NHEAD);

    // stage q row (64 elems) into LDS
    qs[wave][lane] = q[((size_t)(b * SEQ + s)) * HDN + h * HDIM + lane];
    __syncthreads();

    const float* krow_base = &kf[(((size_t)b * NHEAD + h) * TKV) * HDIM];

    // pass 1: raw scores into LDS, track max
    float mymax = -1e30f;
    for (int i = 0; i < 9; ++i) {
        int t = lane + i * 64;
        if (t < TKV) {
            const float* kr = &krow_base[(size_t)t * HDIM];
            float dot = 0.0f;
            #pragma unroll
            for (int d4 = 0; d4 < 16; ++d4) {
                float4 k4 = *(const float4*)&kr[d4 * 4];
                dot = fmaf(qs[wave][d4 * 4 + 0], k4.x, dot);
                dot = fmaf(qs[wave][d4 * 4 + 1], k4.y, dot);
                dot = fmaf(qs[wave][d4 * 4 + 2], k4.z, dot);
                dot = fmaf(qs[wave][d4 * 4 + 3], k4.w, dot);
            }
            float add = (t < LPAST) ? 1.0f : mask[(size_t)b * SEQ + (t - LPAST)];
            float sc = dot * 0.125f + add;
            ps[wave][t] = sc;
            mymax = fmaxf(mymax, sc);
        }
    }
    #pragma unroll
    for (int off = 32; off > 0; off >>= 1)
        mymax = fmaxf(mymax, __shfl_xor(mymax, off));

    // pass 2: exp, sum
    float mysum = 0.0f;
    for (int i = 0; i < 9; ++i) {
        int t = lane + i * 64;
        if (t < TKV) {
            float p = __expf(ps[wave][t] - mymax) ;
            p = expf(ps[wave][t] - mymax);   // exact expf for accuracy
            ps[wave][t] = p;
            mysum += p;
        }
    }
    #pragma unroll
    for (int off = 32; off > 0; off >>= 1)
        mysum += __shfl_xor(mysum, off);
    __syncthreads();

    // PV: lane owns output dim d = lane
    const float* vrow = &vf[(((size_t)b * NHEAD + h) * TKV) * HDIM];
    float acc = 0.0f;
    #pragma unroll 4
    for (int t = 0; t < TKV; ++t)
        acc = fmaf(ps[wave][t], vrow[(size_t)t * HDIM + lane], acc);

    ctx[((size_t)(b * SEQ + s)) * HDN + h * HDIM + lane] = acc / mysum;
}

// ---------------------------------------------------------------------------
// LayerNorm over last dim (768). One block (256 threads) per row, 3 elems each.
// ---------------------------------------------------------------------------
__global__ __launch_bounds__(256) void layernorm_k(
    const float* __restrict__ x, const float* __restrict__ g,
    const float* __restrict__ b, float* __restrict__ out)
{
    const size_t row = blockIdx.x;
    const float* xr = &x[row * HDN];
    const int t = threadIdx.x;

    float v0 = xr[t], v1 = xr[t + 256], v2 = xr[t + 512];

    __shared__ float red[4];
    float s = v0 + v1 + v2;
    #pragma unroll
    for (int off = 32; off > 0; off >>= 1) s += __shfl_xor(s, off);
    if ((t & 63) == 0) red[t >> 6] = s;
    __syncthreads();
    float mean = (red[0] + red[1] + red[2] + red[3]) * (1.0f / 768.0f);

    float d0 = v0 - mean, d1 = v1 - mean, d2 = v2 - mean;
    float vs = d0 * d0 + d1 * d1 + d2 * d2;
    #pragma unroll
    for (int off = 32; off > 0; off >>= 1) vs += __shfl_xor(vs, off);
    __syncthreads();                 // all reads of red[] done
    if ((t & 63) == 0) red[t >> 6] = vs;
    __syncthreads();
    float var = (red[0] + red[1] + red[2] + red[3]) * (1.0f / 768.0f);
    float rstd = rsqrtf(var + 1e-12f);

    out[row * HDN + t]       = d0 * rstd * g[t]       + b[t];
    out[row * HDN + t + 256] = d1 * rstd * g[t + 256] + b[t + 256];
    out[row * HDN + t + 512] = d2 * rstd * g[t + 512] + b[t + 512];
}

// ---------------------------------------------------------------------------
extern "C" void kernel_launch(void* const* d_in, const int* in_sizes, int n_in,
                              void* d_out, int out_size, void* d_ws, size_t ws_size,
                              hipStream_t stream) {
    const float* hs       = (const float*)d_in[0];
    const float* mask     = (const float*)d_in[1];
    const float* past_key = (const float*)d_in[2];
    // d_in[3] past_value: unused (faithful to reference bug)
    const float* Wq = (const float*)d_in[4];
    const float* bq = (const float*)d_in[5];
    const float* Wk = (const float*)d_in[6];
    const float* bk = (const float*)d_in[7];
    const float* Wv = (const float*)d_in[8];
    const float* bv = (const float*)d_in[9];
    const float* Wo = (const float*)d_in[10];
    const float* bo = (const float*)d_in[11];
    const float* ln1_g = (const float*)d_in[12];
    const float* ln1_b = (const float*)d_in[13];
    const float* Wi = (const float*)d_in[14];
    const float* bi = (const float*)d_in[15];
    const float* Wf = (const float*)d_in[16];
    const float* bf = (const float*)d_in[17];
    const float* ln2_g = (const float*)d_in[18];
    const float* ln2_b = (const float*)d_in[19];
    float* out = (float*)d_out;

    float* ws = (float*)d_ws;
    const size_t MH   = (size_t)MTOK * HDN;                    // 6,291,456
    const size_t KVSZ = (size_t)NBATCH * NHEAD * TKV * HDIM;   // 6,905,856

    float* q      = ws;                       // later reused as ctx (safe: per-row RAW within one wave)
    float* kn     = ws + MH;                  // later reused as tmp (pre-LN buffers)
    float* vn     = ws + 2 * MH;              // later reused as attn_ln
    float* kf     = ws + 3 * MH;
    float* vf     = ws + 3 * MH + KVSZ;
    float* interc = ws + 3 * MH + 2 * KVSZ;   // one FFN chunk [M, 768]
    float* ctx     = q;
    float* tmp     = kn;
    float* attn_ln = vn;

    dim3 blk(256);
    dim3 gH(MTOK / 64, HDN / 64);

    // QKV projections
    gemm_f32<0><<<gH, blk, 0, stream>>>(hs, Wq, HDN, bq, nullptr, q,  MTOK, HDN, HDN);
    gemm_f32<0><<<gH, blk, 0, stream>>>(hs, Wk, HDN, bk, nullptr, kn, MTOK, HDN, HDN);
    gemm_f32<0><<<gH, blk, 0, stream>>>(hs, Wv, HDN, bv, nullptr, vn, MTOK, HDN, HDN);

    // KV cache assembly (bug-faithful)
    kv_assemble<<<dim3((unsigned)((KVSZ + 255) / 256)), blk, 0, stream>>>(kn, vn, past_key, kf, vf);

    // attention
    attn_kernel<<<dim3(NBATCH * NHEAD * SEQ / 4), blk, 0, stream>>>(q, kf, vf, mask, ctx);

    // output projection + residual, then LN1
    gemm_f32<1><<<gH, blk, 0, stream>>>(ctx, Wo, HDN, bo, hs, tmp, MTOK, HDN, HDN);
    layernorm_k<<<dim3(MTOK), blk, 0, stream>>>(tmp, ln1_g, ln1_b, attn_ln);

    // FFN in 4 chunks of 768 along FF (bounds workspace to one chunk)
    for (int c = 0; c < 4; ++c) {
        gemm_f32<2><<<gH, blk, 0, stream>>>(
            attn_ln, Wi + c * 768, FFDIM, bi + c * 768, nullptr, interc, MTOK, 768, HDN);
        if (c == 0)
            gemm_f32<1><<<gH, blk, 0, stream>>>(
                interc, Wf + (size_t)c * 768 * HDN, HDN, bf, attn_ln, tmp, MTOK, HDN, 768);
        else
            gemm_f32<3><<<gH, blk, 0, stream>>>(
                interc, Wf + (size_t)c * 768 * HDN, HDN, nullptr, nullptr, tmp, MTOK, HDN, 768);
    }

    // final LN -> output
    layernorm_k<<<dim3(MTOK), blk, 0, stream>>>(tmp, ln2_g, ln2_b, out);
}

// Round 2
// 1208.915 us; speedup vs baseline: 4.1299x; 4.1299x over previous
//
#include <hip/hip_runtime.h>
#include <math.h>

#define HDIM 64
#define NHEAD 12
#define HDN 768
#define FFDIM 3072
#define LPAST 50
#define SEQ 512
#define NBATCH 16
#define TKV (LPAST + SEQ)     // 562
#define MTOK (NBATCH * SEQ)   // 8192
#define NBH (NBATCH * NHEAD)  // 192

typedef __attribute__((ext_vector_type(8))) short short8;
typedef __attribute__((ext_vector_type(4))) float f32x4;

__device__ __forceinline__ ushort f2bf(float x) {
    union { float f; unsigned u; } c; c.f = x;
    unsigned r = (c.u + 0x7fffu + ((c.u >> 16) & 1u)) >> 16;
    return (ushort)r;
}
__device__ __forceinline__ float bflo(unsigned u) { return __uint_as_float(u << 16); }
__device__ __forceinline__ float bfhi(unsigned u) { return __uint_as_float(u & 0xffff0000u); }
__device__ __forceinline__ float geluf(float v) {
    return 0.5f * v * (1.0f + erff(v * 0.70710678118654752f));
}

#define GLOAD_LDS16(gsrc, ldst)                                                    \
    __builtin_amdgcn_global_load_lds(                                              \
        (const __attribute__((address_space(1))) void*)(gsrc),                     \
        (__attribute__((address_space(3))) void*)(ldst), 16, 0, 0)

// ---------------------------------------------------------------------------
// fp32 -> bf16 elementwise cast (vectorized: float4 in, 4x bf16 out)
// ---------------------------------------------------------------------------
__global__ __launch_bounds__(256) void cast_bf(const float* __restrict__ x,
                                               ushort* __restrict__ y, int n4) {
    int i = blockIdx.x * 256 + threadIdx.x;
    if (i >= n4) return;
    float4 v = ((const float4*)x)[i];
    ushort4 o; o.x = f2bf(v.x); o.y = f2bf(v.y); o.z = f2bf(v.z); o.w = f2bf(v.w);
    ((ushort4*)y)[i] = o;
}

// ---------------------------------------------------------------------------
// W[K][N] fp32 -> WT[N][K] bf16  (32x32 LDS tile transpose)
// grid: (N/32, K/32)
// ---------------------------------------------------------------------------
__global__ __launch_bounds__(256) void transpose_cast(const float* __restrict__ W,
                                                      ushort* __restrict__ WT,
                                                      int K, int N) {
    __shared__ float t[32][33];
    const int n0 = blockIdx.x * 32, k0 = blockIdx.y * 32;
    const int tx = threadIdx.x & 31, ty = threadIdx.x >> 5;
    #pragma unroll
    for (int i = 0; i < 4; ++i)
        t[ty + i * 8][tx] = W[(size_t)(k0 + ty + i * 8) * N + n0 + tx];
    __syncthreads();
    #pragma unroll
    for (int i = 0; i < 4; ++i)
        WT[(size_t)(n0 + ty + i * 8) * K + k0 + tx] = f2bf(t[tx][ty + i * 8]);
}

// ---------------------------------------------------------------------------
// bf16 MFMA GEMM (NT): C[M,N] = A[M,K] @ B[N,K]^T   (B = W^T, K-major)
// 128x128 tile, BK=32, 256 threads (4 waves 2x2), 16x16x32 bf16 MFMA.
// EPI: 0 = +bias -> bf16 ; 1 = +bias+resid -> f32 ; 2 = gelu(+bias) -> bf16 ;
//      3 = accumulate into f32 C
// ---------------------------------------------------------------------------
template<int EPI>
__global__ __launch_bounds__(256) void gemm_mfma(
    const ushort* __restrict__ A, const ushort* __restrict__ B,
    int lda, int ldb,
    const float* __restrict__ bias, const float* __restrict__ resid,
    void* __restrict__ Cout, int M, int N, int K)
{
    __shared__ ushort As[128 * 32];
    __shared__ ushort Bs[128 * 32];

    const int tid = threadIdx.x;
    const int lane = tid & 63;
    const int wv = tid >> 6;
    const int wr = wv >> 1, wc = wv & 1;
    const int bm = blockIdx.x * 128, bn = blockIdx.y * 128;
    const int lr = lane & 15, lk = (lane >> 4) * 8;

    f32x4 acc[4][4] = {};

    for (int k0 = 0; k0 < K; k0 += 32) {
        #pragma unroll
        for (int r = 0; r < 2; ++r) {
            int slot = tid + 256 * r;
            int row = slot >> 2, q = slot & 3;
            GLOAD_LDS16(A + (size_t)(bm + row) * lda + k0 + q * 8,
                        (char*)As + slot * 16);
        }
        #pragma unroll
        for (int r = 0; r < 2; ++r) {
            int slot = tid + 256 * r;
            int row = slot >> 2, q = slot & 3;
            GLOAD_LDS16(B + (size_t)(bn + row) * ldb + k0 + q * 8,
                        (char*)Bs + slot * 16);
        }
        __syncthreads();

        short8 af[4], bfv[4];
        #pragma unroll
        for (int i = 0; i < 4; ++i) {
            af[i]  = *(const short8*)&As[(wr * 64 + i * 16 + lr) * 32 + lk];
            bfv[i] = *(const short8*)&Bs[(wc * 64 + i * 16 + lr) * 32 + lk];
        }
        #pragma unroll
        for (int i = 0; i < 4; ++i)
            #pragma unroll
            for (int j = 0; j < 4; ++j)
                acc[i][j] = __builtin_amdgcn_mfma_f32_16x16x32_bf16(
                    af[i], bfv[j], acc[i][j], 0, 0, 0);
        __syncthreads();
    }

    #pragma unroll
    for (int i = 0; i < 4; ++i) {
        #pragma unroll
        for (int j = 0; j < 4; ++j) {
            const int col = bn + wc * 64 + j * 16 + lr;
            float bv = 0.0f;
            if (EPI == 0 || EPI == 1 || EPI == 2) bv = bias[col];
            #pragma unroll
            for (int rr = 0; rr < 4; ++rr) {
                const int row = bm + wr * 64 + i * 16 + (lane >> 4) * 4 + rr;
                const size_t idx = (size_t)row * N + col;
                float v = acc[i][j][rr];
                if (EPI == 0) {
                    ((ushort*)Cout)[idx] = f2bf(v + bv);
                } else if (EPI == 1) {
                    ((float*)Cout)[idx] = v + bv + resid[idx];
                } else if (EPI == 2) {
                    ((ushort*)Cout)[idx] = f2bf(geluf(v + bv));
                } else {
                    ((float*)Cout)[idx] += v;
                }
            }
        }
    }
}

// ---------------------------------------------------------------------------
// K/V cache assembly (bug-faithful: past_key into BOTH), bf16 out.
// kf/vf layout: [bh][TKV][64]
// ---------------------------------------------------------------------------
__global__ __launch_bounds__(256) void kv2(
    const ushort* __restrict__ kbf, const ushort* __restrict__ vbf,
    const float* __restrict__ past_key,
    ushort* __restrict__ kf, ushort* __restrict__ vf)
{
    const size_t total = (size_t)NBH * TKV * HDIM;
    size_t idx = (size_t)blockIdx.x * 256 + threadIdx.x;
    if (idx >= total) return;
    int d = idx & 63;
    size_t r = idx >> 6;
    int t = (int)(r % TKV);
    int bh = (int)(r / TKV);
    ushort kv_, vv;
    if (t < LPAST) {
        float pk = past_key[((size_t)bh * LPAST + t) * HDIM + d];
        kv_ = f2bf(pk); vv = kv_;
    } else {
        int b = bh / NHEAD, h = bh % NHEAD;
        size_t off = ((size_t)(b * SEQ + (t - LPAST))) * HDN + h * HDIM + d;
        kv_ = kbf[off]; vv = vbf[off];
    }
    kf[idx] = kv_; vf[idx] = vv;
}

// ---------------------------------------------------------------------------
// Attention: block = 512 thr (8 waves), one (b,h) + 8 q rows per block.
// K/V staged 64x64-bf16 tiles via global_load_lds, XOR-swizzled source
// (physical slot p holds logical j = p ^ (t&7)). Two-pass softmax in LDS.
// ---------------------------------------------------------------------------
__global__ __launch_bounds__(512) void attn2(
    const ushort* __restrict__ q, const ushort* __restrict__ kf,
    const ushort* __restrict__ vf, const float* __restrict__ mask,
    ushort* __restrict__ ctx)
{
    __shared__ ushort tile[64 * 64];   // 8 KB, reused K then V
    __shared__ float ps[8][576];       // 18 KB raw scores -> probs

    const int wv = threadIdx.x >> 6, lane = threadIdx.x & 63;
    const int blk = blockIdx.x;
    const int bh = blk / (SEQ / 8);
    const int s = (blk % (SEQ / 8)) * 8 + wv;
    const int b = bh / NHEAD, h = bh % NHEAD;
    const size_t qoff = ((size_t)(b * SEQ + s)) * HDN + h * HDIM;

    // q row -> 64 f32 regs (broadcast loads)
    float qf[64];
    const uint4* qp = (const uint4*)(q + qoff);
    #pragma unroll
    for (int i = 0; i < 8; ++i) {
        uint4 u = qp[i];
        qf[i * 8 + 0] = bflo(u.x); qf[i * 8 + 1] = bfhi(u.x);
        qf[i * 8 + 2] = bflo(u.y); qf[i * 8 + 3] = bfhi(u.y);
        qf[i * 8 + 4] = bflo(u.z); qf[i * 8 + 5] = bfhi(u.z);
        qf[i * 8 + 6] = bflo(u.w); qf[i * 8 + 7] = bfhi(u.w);
    }

    const ushort* kbase = kf + (size_t)bh * TKV * HDIM;
    const ushort* vbase = vf + (size_t)bh * TKV * HDIM;

    const int stl = (int)threadIdx.x >> 3;     // staged row 0..63
    const int stp = (int)threadIdx.x & 7;      // physical 16B slot
    const int stj = stp ^ (stl & 7);           // logical 16B slot (involution)

    // ---- pass 1: scores ----
    float mymax = -1e30f;
    for (int kt = 0; kt < 9; ++kt) {
        int tg = kt * 64 + stl;
        int tc = tg < TKV ? tg : TKV - 1;
        GLOAD_LDS16(kbase + ((size_t)tc << 6) + stj * 8,
                    (char*)tile + threadIdx.x * 16);
        __syncthreads();

        float dot = 0.0f;
        #pragma unroll
        for (int jb = 0; jb < 8; ++jb) {
            int slot = jb ^ (lane & 7);
            uint4 kvv = *(const uint4*)&tile[(lane << 6) + slot * 8];
            dot = fmaf(bflo(kvv.x), qf[jb * 8 + 0], dot);
            dot = fmaf(bfhi(kvv.x), qf[jb * 8 + 1], dot);
            dot = fmaf(bflo(kvv.y), qf[jb * 8 + 2], dot);
            dot = fmaf(bfhi(kvv.y), qf[jb * 8 + 3], dot);
            dot = fmaf(bflo(kvv.z), qf[jb * 8 + 4], dot);
            dot = fmaf(bfhi(kvv.z), qf[jb * 8 + 5], dot);
            dot = fmaf(bflo(kvv.w), qf[jb * 8 + 6], dot);
            dot = fmaf(bfhi(kvv.w), qf[jb * 8 + 7], dot);
        }
        int tq = kt * 64 + lane;
        float sc = -1e30f;
        if (tq < TKV) {
            float add = (tq < LPAST) ? 1.0f : mask[(size_t)b * SEQ + (tq - LPAST)];
            sc = dot * 0.125f + add;
        }
        ps[wv][kt * 64 + lane] = sc;
        mymax = fmaxf(mymax, sc);
        __syncthreads();
    }

    #pragma unroll
    for (int off = 32; off > 0; off >>= 1)
        mymax = fmaxf(mymax, __shfl_xor(mymax, off));

    // ---- softmax (per-wave; ps rows are private to the wave) ----
    float mysum = 0.0f;
    #pragma unroll
    for (int kt = 0; kt < 9; ++kt) {
        float p = expf(ps[wv][kt * 64 + lane] - mymax);
        ps[wv][kt * 64 + lane] = p;
        mysum += p;
    }
    #pragma unroll
    for (int off = 32; off > 0; off >>= 1)
        mysum += __shfl_xor(mysum, off);
    const float rs = 1.0f / mysum;

    // ---- pass 2: PV.  lane = (tgroup 0..7) * 8 + (dblk 0..7) ----
    const int dblk = lane & 7, tg8 = lane >> 3;
    float av[8] = {};
    for (int kt = 0; kt < 9; ++kt) {
        int tg = kt * 64 + stl;
        int tc = tg < TKV ? tg : TKV - 1;
        GLOAD_LDS16(vbase + ((size_t)tc << 6) + stj * 8,
                    (char*)tile + threadIdx.x * 16);
        __syncthreads();

        #pragma unroll
        for (int i = 0; i < 8; ++i) {
            int tl = tg8 * 8 + i;
            int slot = dblk ^ i;               // (tl & 7) == i
            uint4 v16 = *(const uint4*)&tile[(tl << 6) + slot * 8];
            float p = ps[wv][kt * 64 + tl];
            av[0] = fmaf(p, bflo(v16.x), av[0]);
            av[1] = fmaf(p, bfhi(v16.x), av[1]);
            av[2] = fmaf(p, bflo(v16.y), av[2]);
            av[3] = fmaf(p, bfhi(v16.y), av[3]);
            av[4] = fmaf(p, bflo(v16.z), av[4]);
            av[5] = fmaf(p, bfhi(v16.z), av[5]);
            av[6] = fmaf(p, bflo(v16.w), av[6]);
            av[7] = fmaf(p, bfhi(v16.w), av[7]);
        }
        __syncthreads();
    }

    #pragma unroll
    for (int off = 8; off <= 32; off <<= 1)
        #pragma unroll
        for (int e = 0; e < 8; ++e)
            av[e] += __shfl_xor(av[e], off);

    if (tg8 == 0) {
        uint4 o;
        o.x = (unsigned)f2bf(av[0] * rs) | ((unsigned)f2bf(av[1] * rs) << 16);
        o.y = (unsigned)f2bf(av[2] * rs) | ((unsigned)f2bf(av[3] * rs) << 16);
        o.z = (unsigned)f2bf(av[4] * rs) | ((unsigned)f2bf(av[5] * rs) << 16);
        o.w = (unsigned)f2bf(av[6] * rs) | ((unsigned)f2bf(av[7] * rs) << 16);
        *(uint4*)(ctx + qoff + dblk * 8) = o;
    }
}

// ---------------------------------------------------------------------------
// LayerNorm(768), optional extra bf16 output.
// ---------------------------------------------------------------------------
__global__ __launch_bounds__(256) void layernorm2(
    const float* __restrict__ x, const float* __restrict__ g,
    const float* __restrict__ b, float* __restrict__ out,
    ushort* __restrict__ out_bf)
{
    const size_t row = blockIdx.x;
    const float* xr = &x[row * HDN];
    const int t = threadIdx.x;

    float v0 = xr[t], v1 = xr[t + 256], v2 = xr[t + 512];

    __shared__ float red[4];
    float s = v0 + v1 + v2;
    #pragma unroll
    for (int off = 32; off > 0; off >>= 1) s += __shfl_xor(s, off);
    if ((t & 63) == 0) red[t >> 6] = s;
    __syncthreads();
    float mean = (red[0] + red[1] + red[2] + red[3]) * (1.0f / 768.0f);

    float d0 = v0 - mean, d1 = v1 - mean, d2 = v2 - mean;
    float vs = d0 * d0 + d1 * d1 + d2 * d2;
    #pragma unroll
    for (int off = 32; off > 0; off >>= 1) vs += __shfl_xor(vs, off);
    __syncthreads();
    if ((t & 63) == 0) red[t >> 6] = vs;
    __syncthreads();
    float var = (red[0] + red[1] + red[2] + red[3]) * (1.0f / 768.0f);
    float rstd = rsqrtf(var + 1e-12f);

    float o0 = d0 * rstd * g[t] + b[t];
    float o1 = d1 * rstd * g[t + 256] + b[t + 256];
    float o2 = d2 * rstd * g[t + 512] + b[t + 512];
    out[row * HDN + t] = o0;
    out[row * HDN + t + 256] = o1;
    out[row * HDN + t + 512] = o2;
    if (out_bf) {
        out_bf[row * HDN + t] = f2bf(o0);
        out_bf[row * HDN + t + 256] = f2bf(o1);
        out_bf[row * HDN + t + 512] = f2bf(o2);
    }
}

// ---------------------------------------------------------------------------
extern "C" void kernel_launch(void* const* d_in, const int* in_sizes, int n_in,
                              void* d_out, int out_size, void* d_ws, size_t ws_size,
                              hipStream_t stream) {
    const float* hs       = (const float*)d_in[0];
    const float* mask     = (const float*)d_in[1];
    const float* past_key = (const float*)d_in[2];
    const float* Wq = (const float*)d_in[4];
    const float* bq = (const float*)d_in[5];
    const float* Wk = (const float*)d_in[6];
    const float* bk = (const float*)d_in[7];
    const float* Wv = (const float*)d_in[8];
    const float* bv = (const float*)d_in[9];
    const float* Wo = (const float*)d_in[10];
    const float* bo = (const float*)d_in[11];
    const float* ln1_g = (const float*)d_in[12];
    const float* ln1_b = (const float*)d_in[13];
    const float* Wi = (const float*)d_in[14];
    const float* bi = (const float*)d_in[15];
    const float* Wf = (const float*)d_in[16];
    const float* bf_ = (const float*)d_in[17];
    const float* ln2_g = (const float*)d_in[18];
    const float* ln2_b = (const float*)d_in[19];
    float* out = (float*)d_out;

    char* w = (char*)d_ws;
    // byte offsets (see planning): total use ~105 MB
    ushort* WqT   = (ushort*)(w + 0);
    ushort* WkT   = (ushort*)(w + 1179648);
    ushort* WvT   = (ushort*)(w + 2359296);
    ushort* WoT   = (ushort*)(w + 3538944);
    ushort* WiT   = (ushort*)(w + 4718592);   // [3072][768]
    ushort* WfT   = (ushort*)(w + 9437184);   // [768][3072]
    ushort* hs_bf = (ushort*)(w + 14155776);
    ushort* q_bf  = (ushort*)(w + 26738688);
    ushort* k_bf  = (ushort*)(w + 39321600);  // reused as ctx_bf
    ushort* v_bf  = (ushort*)(w + 51904512);  // reused as attn_ln_bf
    ushort* kf    = (ushort*)(w + 64487424);
    ushort* vf    = (ushort*)(w + 78299136);
    float*  tmp   = (float*)(w + 64487424);   // overlays kf/vf (dead by then)
    float*  aln   = (float*)(w + 14155776);   // overlays hs_bf+q_bf (dead)
    ushort* inter = (ushort*)(w + 92110848);
    ushort* ctx_bf = k_bf;
    ushort* aln_bf = v_bf;

    dim3 b256(256);

    // casts + weight transposes
    cast_bf<<<dim3((MTOK * HDN / 4 + 255) / 256), b256, 0, stream>>>(hs, hs_bf, MTOK * HDN / 4);
    transpose_cast<<<dim3(24, 24), b256, 0, stream>>>(Wq, WqT, HDN, HDN);
    transpose_cast<<<dim3(24, 24), b256, 0, stream>>>(Wk, WkT, HDN, HDN);
    transpose_cast<<<dim3(24, 24), b256, 0, stream>>>(Wv, WvT, HDN, HDN);
    transpose_cast<<<dim3(24, 24), b256, 0, stream>>>(Wo, WoT, HDN, HDN);
    transpose_cast<<<dim3(96, 24), b256, 0, stream>>>(Wi, WiT, HDN, FFDIM);
    transpose_cast<<<dim3(24, 96), b256, 0, stream>>>(Wf, WfT, FFDIM, HDN);

    dim3 gH(MTOK / 128, HDN / 128);  // (64, 6)

    // QKV projections -> bf16
    gemm_mfma<0><<<gH, b256, 0, stream>>>(hs_bf, WqT, HDN, HDN, bq, nullptr, q_bf, MTOK, HDN, HDN);
    gemm_mfma<0><<<gH, b256, 0, stream>>>(hs_bf, WkT, HDN, HDN, bk, nullptr, k_bf, MTOK, HDN, HDN);
    gemm_mfma<0><<<gH, b256, 0, stream>>>(hs_bf, WvT, HDN, HDN, bv, nullptr, v_bf, MTOK, HDN, HDN);

    // KV cache (bug-faithful)
    {
        size_t kvtot = (size_t)NBH * TKV * HDIM;
        kv2<<<dim3((unsigned)((kvtot + 255) / 256)), b256, 0, stream>>>(k_bf, v_bf, past_key, kf, vf);
    }

    // attention
    attn2<<<dim3(NBH * (SEQ / 8)), dim3(512), 0, stream>>>(q_bf, kf, vf, mask, ctx_bf);

    // output projection + residual(hs) -> f32 tmp ; LN1
    gemm_mfma<1><<<gH, b256, 0, stream>>>(ctx_bf, WoT, HDN, HDN, bo, hs, tmp, MTOK, HDN, HDN);
    layernorm2<<<dim3(MTOK), b256, 0, stream>>>(tmp, ln1_g, ln1_b, aln, aln_bf);

    // FFN: 4 chunks of 768 along FF
    for (int c = 0; c < 4; ++c) {
        gemm_mfma<2><<<gH, b256, 0, stream>>>(
            aln_bf, WiT + (size_t)c * 768 * HDN, HDN, HDN,
            bi + c * 768, nullptr, inter, MTOK, HDN, HDN);
        if (c == 0)
            gemm_mfma<1><<<gH, b256, 0, stream>>>(
                inter, WfT + (size_t)c * 768, HDN, FFDIM,
                bf_, aln, tmp, MTOK, HDN, HDN);
        else
            gemm_mfma<3><<<gH, b256, 0, stream>>>(
                inter, WfT + (size_t)c * 768, HDN, FFDIM,
                nullptr, nullptr, tmp, MTOK, HDN, HDN);
    }

    // final LN -> out
    layernorm2<<<dim3(MTOK), b256, 0, stream>>>(tmp, ln2_g, ln2_b, out, nullptr);
}

// Round 3
// 461.659 us; speedup vs baseline: 10.8147x; 2.6186x over previous
//
#include <hip/hip_runtime.h>
#include <math.h>

#define HDIM 64
#define NHEAD 12
#define HDN 768
#define FFDIM 3072
#define LPAST 50
#define SEQ 512
#define NBATCH 16
#define TKV (LPAST + SEQ)     // 562
#define TKVP 576              // padded keys (9*64)
#define MTOK (NBATCH * SEQ)   // 8192
#define NBH (NBATCH * NHEAD)  // 192

typedef __attribute__((ext_vector_type(8))) short short8;
typedef __attribute__((ext_vector_type(4))) float f32x4;

__device__ __forceinline__ ushort f2bf(float x) {
    union { float f; unsigned u; } c; c.f = x;
    unsigned r = (c.u + 0x7fffu + ((c.u >> 16) & 1u)) >> 16;
    return (ushort)r;
}
__device__ __forceinline__ float bflo(unsigned u) { return __uint_as_float(u << 16); }
__device__ __forceinline__ float bfhi(unsigned u) { return __uint_as_float(u & 0xffff0000u); }
__device__ __forceinline__ float geluf(float v) {
    return 0.5f * v * (1.0f + erff(v * 0.70710678118654752f));
}

#define GLOAD_LDS16(gsrc, ldst)                                                    \
    __builtin_amdgcn_global_load_lds(                                              \
        (const __attribute__((address_space(1))) void*)(gsrc),                     \
        (__attribute__((address_space(3))) void*)(ldst), 16, 0, 0)

// ---------------------------------------------------------------------------
// fp32 -> bf16 elementwise cast
// ---------------------------------------------------------------------------
__global__ __launch_bounds__(256) void cast_bf(const float* __restrict__ x,
                                               ushort* __restrict__ y, int n4) {
    int i = blockIdx.x * 256 + threadIdx.x;
    if (i >= n4) return;
    float4 v = ((const float4*)x)[i];
    ushort4 o; o.x = f2bf(v.x); o.y = f2bf(v.y); o.z = f2bf(v.z); o.w = f2bf(v.w);
    ((ushort4*)y)[i] = o;
}

// ---------------------------------------------------------------------------
// W[K][N] fp32 -> WT[N][K] bf16
// ---------------------------------------------------------------------------
__global__ __launch_bounds__(256) void transpose_cast(const float* __restrict__ W,
                                                      ushort* __restrict__ WT,
                                                      int K, int N) {
    __shared__ float t[32][33];
    const int n0 = blockIdx.x * 32, k0 = blockIdx.y * 32;
    const int tx = threadIdx.x & 31, ty = threadIdx.x >> 5;
    #pragma unroll
    for (int i = 0; i < 4; ++i)
        t[ty + i * 8][tx] = W[(size_t)(k0 + ty + i * 8) * N + n0 + tx];
    __syncthreads();
    #pragma unroll
    for (int i = 0; i < 4; ++i)
        WT[(size_t)(n0 + ty + i * 8) * K + k0 + tx] = f2bf(t[tx][ty + i * 8]);
}

// ---------------------------------------------------------------------------
// bf16 MFMA GEMM (NT): C[M,N] = A[M,K] @ B[N,K]^T
// EPI: 0 = +bias->bf16 ; 1 = +bias+resid->f32 ; 2 = gelu(+bias)->bf16 ; 3 = accum f32
// ---------------------------------------------------------------------------
template<int EPI>
__global__ __launch_bounds__(256) void gemm_mfma(
    const ushort* __restrict__ A, const ushort* __restrict__ B,
    int lda, int ldb,
    const float* __restrict__ bias, const float* __restrict__ resid,
    void* __restrict__ Cout, int M, int N, int K)
{
    __shared__ ushort As[128 * 32];
    __shared__ ushort Bs[128 * 32];

    const int tid = threadIdx.x;
    const int lane = tid & 63;
    const int wv = tid >> 6;
    const int wr = wv >> 1, wc = wv & 1;
    const int bm = blockIdx.x * 128, bn = blockIdx.y * 128;
    const int lr = lane & 15, lk = (lane >> 4) * 8;

    f32x4 acc[4][4] = {};

    for (int k0 = 0; k0 < K; k0 += 32) {
        #pragma unroll
        for (int r = 0; r < 2; ++r) {
            int slot = tid + 256 * r;
            int row = slot >> 2, q = slot & 3;
            GLOAD_LDS16(A + (size_t)(bm + row) * lda + k0 + q * 8,
                        (char*)As + slot * 16);
        }
        #pragma unroll
        for (int r = 0; r < 2; ++r) {
            int slot = tid + 256 * r;
            int row = slot >> 2, q = slot & 3;
            GLOAD_LDS16(B + (size_t)(bn + row) * ldb + k0 + q * 8,
                        (char*)Bs + slot * 16);
        }
        __syncthreads();

        short8 af[4], bfv[4];
        #pragma unroll
        for (int i = 0; i < 4; ++i) {
            af[i]  = *(const short8*)&As[(wr * 64 + i * 16 + lr) * 32 + lk];
            bfv[i] = *(const short8*)&Bs[(wc * 64 + i * 16 + lr) * 32 + lk];
        }
        #pragma unroll
        for (int i = 0; i < 4; ++i)
            #pragma unroll
            for (int j = 0; j < 4; ++j)
                acc[i][j] = __builtin_amdgcn_mfma_f32_16x16x32_bf16(
                    af[i], bfv[j], acc[i][j], 0, 0, 0);
        __syncthreads();
    }

    #pragma unroll
    for (int i = 0; i < 4; ++i) {
        #pragma unroll
        for (int j = 0; j < 4; ++j) {
            const int col = bn + wc * 64 + j * 16 + lr;
            float bv = 0.0f;
            if (EPI == 0 || EPI == 1 || EPI == 2) bv = bias[col];
            #pragma unroll
            for (int rr = 0; rr < 4; ++rr) {
                const int row = bm + wr * 64 + i * 16 + (lane >> 4) * 4 + rr;
                const size_t idx = (size_t)row * N + col;
                float v = acc[i][j][rr];
                if (EPI == 0) {
                    ((ushort*)Cout)[idx] = f2bf(v + bv);
                } else if (EPI == 1) {
                    ((float*)Cout)[idx] = v + bv + resid[idx];
                } else if (EPI == 2) {
                    ((ushort*)Cout)[idx] = f2bf(geluf(v + bv));
                } else {
                    ((float*)Cout)[idx] += v;
                }
            }
        }
    }
}

// ---------------------------------------------------------------------------
// K cache assembly (bug-faithful: past_key prepended). kf: [bh][TKV][64] bf16
// ---------------------------------------------------------------------------
__global__ __launch_bounds__(256) void kvK(
    const ushort* __restrict__ kbf, const float* __restrict__ past_key,
    ushort* __restrict__ kf)
{
    const size_t total = (size_t)NBH * TKV * HDIM;
    size_t idx = (size_t)blockIdx.x * 256 + threadIdx.x;
    if (idx >= total) return;
    int d = idx & 63;
    size_t r = idx >> 6;
    int t = (int)(r % TKV);
    int bh = (int)(r / TKV);
    ushort kv_;
    if (t < LPAST) {
        kv_ = f2bf(past_key[((size_t)bh * LPAST + t) * HDIM + d]);
    } else {
        int b = bh / NHEAD, h = bh % NHEAD;
        kv_ = kbf[((size_t)(b * SEQ + (t - LPAST))) * HDN + h * HDIM + d];
    }
    kf[idx] = kv_;
}

// ---------------------------------------------------------------------------
// V cache, TRANSPOSED (bug-faithful: past_key is the prefix of v too).
// vt: [bh][64 d][TKVP keys] bf16, zero-padded keys >= TKV.
// grid: bh * 9 key-tiles; 64x64 LDS transpose.
// ---------------------------------------------------------------------------
__global__ __launch_bounds__(256) void kvVT(
    const ushort* __restrict__ vbf, const float* __restrict__ past_key,
    ushort* __restrict__ vt)
{
    __shared__ ushort td[64][72];
    const int bh = blockIdx.x / 9;
    const int t0 = (blockIdx.x % 9) * 64;
    const int b = bh / NHEAD, h = bh % NHEAD;
    const int trow = threadIdx.x >> 2, seg = threadIdx.x & 3;
    const int t = t0 + trow;

    ushort vals[16];
    if (t < LPAST) {
        const float* pk = past_key + ((size_t)bh * LPAST + t) * HDIM + seg * 16;
        #pragma unroll
        for (int i = 0; i < 4; ++i) {
            float4 f = ((const float4*)pk)[i];
            vals[i * 4 + 0] = f2bf(f.x); vals[i * 4 + 1] = f2bf(f.y);
            vals[i * 4 + 2] = f2bf(f.z); vals[i * 4 + 3] = f2bf(f.w);
        }
    } else if (t < TKV) {
        const ushort* vp = vbf + ((size_t)(b * SEQ + (t - LPAST))) * HDN + h * HDIM + seg * 16;
        uint4 u0 = ((const uint4*)vp)[0], u1 = ((const uint4*)vp)[1];
        *(uint4*)&vals[0] = u0; *(uint4*)&vals[8] = u1;
    } else {
        #pragma unroll
        for (int i = 0; i < 16; ++i) vals[i] = 0;
    }
    #pragma unroll
    for (int i = 0; i < 16; ++i) td[trow][seg * 16 + i] = vals[i];
    __syncthreads();

    const int d = threadIdx.x >> 2;
    ushort o[16];
    #pragma unroll
    for (int i = 0; i < 16; ++i) o[i] = td[seg * 16 + i][d];
    ushort* dst = vt + ((size_t)bh * HDIM + d) * TKVP + t0 + seg * 16;
    *(uint4*)dst = *(uint4*)&o[0];
    *(uint4*)(dst + 8) = *(uint4*)&o[8];
}

// ---------------------------------------------------------------------------
// MFMA flash attention.
// Block = 256 thr (4 waves), one (b,h), 64 q rows (wave owns 16).
// 9 K-tiles of 64 keys. K tile [64 key][64 d], V^T tile [64 d][64 key],
// both staged via global_load_lds with XOR-pre-swizzled source
// (physical 16B slot p of row holds logical chunk p ^ (row&7)).
// Online softmax in registers; P relayout via per-wave swizzled LDS tile.
// ---------------------------------------------------------------------------
__global__ __launch_bounds__(256) void attn3(
    const ushort* __restrict__ q, const ushort* __restrict__ kf,
    const ushort* __restrict__ vt, const float* __restrict__ mask,
    ushort* __restrict__ ctx)
{
    __shared__ ushort Ks[64 * 64];
    __shared__ ushort Vs[64 * 64];
    __shared__ ushort Ps[4][16 * 64];

    const int wv = threadIdx.x >> 6, lane = threadIdx.x & 63;
    const int lr = lane & 15, lg = lane >> 4;
    const int bh = blockIdx.x >> 3;
    const int s0 = (blockIdx.x & 7) * 64;
    const int b = bh / NHEAD, h = bh % NHEAD;

    // Q A-frags: A[q=lr][k-chunk lg*8 (+c*32)]
    short8 af[2];
    {
        const ushort* qp = q + ((size_t)(b * SEQ + s0 + wv * 16 + lr)) * HDN
                             + h * HDIM + lg * 8;
        af[0] = *(const short8*)qp;
        af[1] = *(const short8*)(qp + 32);
    }

    const ushort* kbase = kf + (size_t)bh * TKV * HDIM;
    const ushort* vbase = vt + (size_t)bh * HDIM * TKVP;

    float m[4] = {-1e30f, -1e30f, -1e30f, -1e30f};
    float l[4] = {};
    f32x4 ctxa[4] = {};

    for (int kt = 0; kt < 9; ++kt) {
        const int t0 = kt * 64;
        #pragma unroll
        for (int r = 0; r < 2; ++r) {
            int sl = (int)threadIdx.x + 256 * r;
            int row = sl >> 3, p = sl & 7;
            int j = p ^ (row & 7);
            int trow = t0 + row; if (trow > TKV - 1) trow = TKV - 1;
            GLOAD_LDS16(kbase + ((size_t)trow << 6) + j * 8, (char*)Ks + sl * 16);
        }
        #pragma unroll
        for (int r = 0; r < 2; ++r) {
            int sl = (int)threadIdx.x + 256 * r;
            int row = sl >> 3, p = sl & 7;     // row = d
            int j = p ^ (row & 7);
            GLOAD_LDS16(vbase + (size_t)row * TKVP + t0 + j * 8, (char*)Vs + sl * 16);
        }
        __syncthreads();

        // ---- scores: S[q][key] for this wave's 16 q rows, 64 keys ----
        f32x4 sa[4] = {};
        #pragma unroll
        for (int kb = 0; kb < 4; ++kb) {
            const int key = kb * 16 + lr;
            #pragma unroll
            for (int c = 0; c < 2; ++c) {
                const int phys = (c * 4 + lg) ^ (key & 7);
                short8 kfrag = *(const short8*)&Ks[key * 64 + phys * 8];
                sa[kb] = __builtin_amdgcn_mfma_f32_16x16x32_bf16(
                    af[c], kfrag, sa[kb], 0, 0, 0);
            }
        }

        // scale + mask (+1 for visual prefix, faithful), tail kill
        float scv[4][4];
        #pragma unroll
        for (int kb = 0; kb < 4; ++kb) {
            const int t = t0 + kb * 16 + lr;
            float add = 0.0f;
            bool dead = (t >= TKV);
            if (!dead) add = (t < LPAST) ? 1.0f : mask[(size_t)b * SEQ + (t - LPAST)];
            #pragma unroll
            for (int r = 0; r < 4; ++r)
                scv[kb][r] = dead ? -1e30f : fmaf(sa[kb][r], 0.125f, add);
        }

        // online softmax per row r (q = lg*4 + r)
        #pragma unroll
        for (int r = 0; r < 4; ++r) {
            float mx = fmaxf(fmaxf(scv[0][r], scv[1][r]), fmaxf(scv[2][r], scv[3][r]));
            mx = fmaxf(mx, __shfl_xor(mx, 1));
            mx = fmaxf(mx, __shfl_xor(mx, 2));
            mx = fmaxf(mx, __shfl_xor(mx, 4));
            mx = fmaxf(mx, __shfl_xor(mx, 8));
            const float mn = fmaxf(m[r], mx);
            const float f = __expf(m[r] - mn);
            m[r] = mn;
            l[r] *= f;
            #pragma unroll
            for (int dg = 0; dg < 4; ++dg) ctxa[dg][r] *= f;
            const int q_ = lg * 4 + r;
            #pragma unroll
            for (int kb = 0; kb < 4; ++kb) {
                float p = __expf(scv[kb][r] - mn);
                l[r] += p;
                const int key = kb * 16 + lr;
                const int phys = (key >> 3) ^ (q_ & 7);
                Ps[wv][q_ * 64 + phys * 8 + (key & 7)] = f2bf(p);
            }
        }

        // ---- PV: ctx[q][d] += P[q][keys] @ V^T[d][keys]^T ----
        short8 pa[2];
        #pragma unroll
        for (int c = 0; c < 2; ++c) {
            const int phys = (c * 4 + lg) ^ (lr & 7);
            pa[c] = *(const short8*)&Ps[wv][lr * 64 + phys * 8];
        }
        #pragma unroll
        for (int dg = 0; dg < 4; ++dg) {
            const int d = dg * 16 + lr;
            #pragma unroll
            for (int c = 0; c < 2; ++c) {
                const int phys = (c * 4 + lg) ^ (d & 7);
                short8 vfrag = *(const short8*)&Vs[d * 64 + phys * 8];
                ctxa[dg] = __builtin_amdgcn_mfma_f32_16x16x32_bf16(
                    pa[c], vfrag, ctxa[dg], 0, 0, 0);
            }
        }
        __syncthreads();
    }

    // normalize + write
    #pragma unroll
    for (int r = 0; r < 4; ++r) {
        float s = l[r];
        s += __shfl_xor(s, 1); s += __shfl_xor(s, 2);
        s += __shfl_xor(s, 4); s += __shfl_xor(s, 8);
        l[r] = 1.0f / s;
    }
    #pragma unroll
    for (int r = 0; r < 4; ++r) {
        const int q_ = s0 + wv * 16 + lg * 4 + r;
        const size_t base = ((size_t)(b * SEQ + q_)) * HDN + h * HDIM;
        #pragma unroll
        for (int dg = 0; dg < 4; ++dg)
            ctx[base + dg * 16 + lr] = f2bf(ctxa[dg][r] * l[r]);
    }
}

// ---------------------------------------------------------------------------
// LayerNorm(768), optional extra bf16 output.
// ---------------------------------------------------------------------------
__global__ __launch_bounds__(256) void layernorm2(
    const float* __restrict__ x, const float* __restrict__ g,
    const float* __restrict__ b, float* __restrict__ out,
    ushort* __restrict__ out_bf)
{
    const size_t row = blockIdx.x;
    const float* xr = &x[row * HDN];
    const int t = threadIdx.x;

    float v0 = xr[t], v1 = xr[t + 256], v2 = xr[t + 512];

    __shared__ float red[4];
    float s = v0 + v1 + v2;
    #pragma unroll
    for (int off = 32; off > 0; off >>= 1) s += __shfl_xor(s, off);
    if ((t & 63) == 0) red[t >> 6] = s;
    __syncthreads();
    float mean = (red[0] + red[1] + red[2] + red[3]) * (1.0f / 768.0f);

    float d0 = v0 - mean, d1 = v1 - mean, d2 = v2 - mean;
    float vs = d0 * d0 + d1 * d1 + d2 * d2;
    #pragma unroll
    for (int off = 32; off > 0; off >>= 1) vs += __shfl_xor(vs, off);
    __syncthreads();
    if ((t & 63) == 0) red[t >> 6] = vs;
    __syncthreads();
    float var = (red[0] + red[1] + red[2] + red[3]) * (1.0f / 768.0f);
    float rstd = rsqrtf(var + 1e-12f);

    float o0 = d0 * rstd * g[t] + b[t];
    float o1 = d1 * rstd * g[t + 256] + b[t + 256];
    float o2 = d2 * rstd * g[t + 512] + b[t + 512];
    out[row * HDN + t] = o0;
    out[row * HDN + t + 256] = o1;
    out[row * HDN + t + 512] = o2;
    if (out_bf) {
        out_bf[row * HDN + t] = f2bf(o0);
        out_bf[row * HDN + t + 256] = f2bf(o1);
        out_bf[row * HDN + t + 512] = f2bf(o2);
    }
}

// ---------------------------------------------------------------------------
extern "C" void kernel_launch(void* const* d_in, const int* in_sizes, int n_in,
                              void* d_out, int out_size, void* d_ws, size_t ws_size,
                              hipStream_t stream) {
    const float* hs       = (const float*)d_in[0];
    const float* mask     = (const float*)d_in[1];
    const float* past_key = (const float*)d_in[2];
    const float* Wq = (const float*)d_in[4];
    const float* bq = (const float*)d_in[5];
    const float* Wk = (const float*)d_in[6];
    const float* bk = (const float*)d_in[7];
    const float* Wv = (const float*)d_in[8];
    const float* bv = (const float*)d_in[9];
    const float* Wo = (const float*)d_in[10];
    const float* bo = (const float*)d_in[11];
    const float* ln1_g = (const float*)d_in[12];
    const float* ln1_b = (const float*)d_in[13];
    const float* Wi = (const float*)d_in[14];
    const float* bi = (const float*)d_in[15];
    const float* Wf = (const float*)d_in[16];
    const float* bf_ = (const float*)d_in[17];
    const float* ln2_g = (const float*)d_in[18];
    const float* ln2_b = (const float*)d_in[19];
    float* out = (float*)d_out;

    char* w = (char*)d_ws;
    ushort* WqT   = (ushort*)(w + 0);
    ushort* WkT   = (ushort*)(w + 1179648);
    ushort* WvT   = (ushort*)(w + 2359296);
    ushort* WoT   = (ushort*)(w + 3538944);
    ushort* WiT   = (ushort*)(w + 4718592);
    ushort* WfT   = (ushort*)(w + 9437184);
    ushort* hs_bf = (ushort*)(w + 14155776);
    ushort* q_bf  = (ushort*)(w + 26738688);
    ushort* k_bf  = (ushort*)(w + 39321600);  // reused as ctx_bf
    ushort* v_bf  = (ushort*)(w + 51904512);  // reused as attn_ln_bf
    ushort* kf    = (ushort*)(w + 64487424);  // 13,811,712 B
    ushort* vt    = (ushort*)(w + 78299136);  // 14,155,776 B (padded 576)
    float*  tmp   = (float*)(w + 64487424);   // overlays kf+vt (dead post-attn)
    float*  aln   = (float*)(w + 14155776);   // overlays hs_bf+q_bf (dead)
    ushort* inter = (ushort*)(w + 92454912);
    ushort* ctx_bf = k_bf;
    ushort* aln_bf = v_bf;

    dim3 b256(256);

    cast_bf<<<dim3((MTOK * HDN / 4 + 255) / 256), b256, 0, stream>>>(hs, hs_bf, MTOK * HDN / 4);
    transpose_cast<<<dim3(24, 24), b256, 0, stream>>>(Wq, WqT, HDN, HDN);
    transpose_cast<<<dim3(24, 24), b256, 0, stream>>>(Wk, WkT, HDN, HDN);
    transpose_cast<<<dim3(24, 24), b256, 0, stream>>>(Wv, WvT, HDN, HDN);
    transpose_cast<<<dim3(24, 24), b256, 0, stream>>>(Wo, WoT, HDN, HDN);
    transpose_cast<<<dim3(96, 24), b256, 0, stream>>>(Wi, WiT, HDN, FFDIM);
    transpose_cast<<<dim3(24, 96), b256, 0, stream>>>(Wf, WfT, FFDIM, HDN);

    dim3 gH(MTOK / 128, HDN / 128);

    gemm_mfma<0><<<gH, b256, 0, stream>>>(hs_bf, WqT, HDN, HDN, bq, nullptr, q_bf, MTOK, HDN, HDN);
    gemm_mfma<0><<<gH, b256, 0, stream>>>(hs_bf, WkT, HDN, HDN, bk, nullptr, k_bf, MTOK, HDN, HDN);
    gemm_mfma<0><<<gH, b256, 0, stream>>>(hs_bf, WvT, HDN, HDN, bv, nullptr, v_bf, MTOK, HDN, HDN);

    {
        size_t ktot = (size_t)NBH * TKV * HDIM;
        kvK<<<dim3((unsigned)((ktot + 255) / 256)), b256, 0, stream>>>(k_bf, past_key, kf);
    }
    kvVT<<<dim3(NBH * 9), b256, 0, stream>>>(v_bf, past_key, vt);

    attn3<<<dim3(NBH * 8), b256, 0, stream>>>(q_bf, kf, vt, mask, ctx_bf);

    gemm_mfma<1><<<gH, b256, 0, stream>>>(ctx_bf, WoT, HDN, HDN, bo, hs, tmp, MTOK, HDN, HDN);
    layernorm2<<<dim3(MTOK), b256, 0, stream>>>(tmp, ln1_g, ln1_b, aln, aln_bf);

    for (int c = 0; c < 4; ++c) {
        gemm_mfma<2><<<gH, b256, 0, stream>>>(
            aln_bf, WiT + (size_t)c * 768 * HDN, HDN, HDN,
            bi + c * 768, nullptr, inter, MTOK, HDN, HDN);
        if (c == 0)
            gemm_mfma<1><<<gH, b256, 0, stream>>>(
                inter, WfT + (size_t)c * 768, HDN, FFDIM,
                bf_, aln, tmp, MTOK, HDN, HDN);
        else
            gemm_mfma<3><<<gH, b256, 0, stream>>>(
                inter, WfT + (size_t)c * 768, HDN, FFDIM,
                nullptr, nullptr, tmp, MTOK, HDN, HDN);
    }

    layernorm2<<<dim3(MTOK), b256, 0, stream>>>(tmp, ln2_g, ln2_b, out, nullptr);
}

// Round 4
// 329.655 us; speedup vs baseline: 15.1452x; 1.4004x over previous
//
#include <hip/hip_runtime.h>
#include <math.h>

#define HDIM 64
#define NHEAD 12
#define HDN 768
#define QKVN 2304
#define FFDIM 3072
#define LPAST 50
#define SEQ 512
#define NBATCH 16
#define TKV (LPAST + SEQ)     // 562
#define TKVP 576
#define MTOK (NBATCH * SEQ)   // 8192
#define NBH (NBATCH * NHEAD)  // 192

typedef __attribute__((ext_vector_type(8))) short short8;
typedef __attribute__((ext_vector_type(4))) float f32x4;

__device__ __forceinline__ ushort f2bf(float x) {
    union { float f; unsigned u; } c; c.f = x;
    unsigned r = (c.u + 0x7fffu + ((c.u >> 16) & 1u)) >> 16;
    return (ushort)r;
}
__device__ __forceinline__ float bf2f(ushort u) { return __uint_as_float((unsigned)u << 16); }
__device__ __forceinline__ float geluf(float v) {
    return 0.5f * v * (1.0f + erff(v * 0.70710678118654752f));
}

#define GLOAD_LDS16(gsrc, ldst)                                                    \
    __builtin_amdgcn_global_load_lds(                                              \
        (const __attribute__((address_space(1))) void*)(gsrc),                     \
        (__attribute__((address_space(3))) void*)(ldst), 16, 0, 0)

// ---------------------------------------------------------------------------
__global__ __launch_bounds__(256) void cast_bf(const float* __restrict__ x,
                                               ushort* __restrict__ y, int n4) {
    int i = blockIdx.x * 256 + threadIdx.x;
    if (i >= n4) return;
    float4 v = ((const float4*)x)[i];
    ushort4 o; o.x = f2bf(v.x); o.y = f2bf(v.y); o.z = f2bf(v.z); o.w = f2bf(v.w);
    ((ushort4*)y)[i] = o;
}

__global__ __launch_bounds__(256) void pack_bias(const float* __restrict__ bq,
                                                 const float* __restrict__ bk,
                                                 const float* __restrict__ bv,
                                                 float* __restrict__ o) {
    int i = blockIdx.x * 256 + threadIdx.x;
    if (i >= QKVN) return;
    o[i] = i < HDN ? bq[i] : (i < 2 * HDN ? bk[i - HDN] : bv[i - 2 * HDN]);
}

// ---------------------------------------------------------------------------
// W[K][N] fp32 -> WT[N][K] bf16
// ---------------------------------------------------------------------------
__global__ __launch_bounds__(256) void transpose_cast(const float* __restrict__ W,
                                                      ushort* __restrict__ WT,
                                                      int K, int N) {
    __shared__ float t[32][33];
    const int n0 = blockIdx.x * 32, k0 = blockIdx.y * 32;
    const int tx = threadIdx.x & 31, ty = threadIdx.x >> 5;
    #pragma unroll
    for (int i = 0; i < 4; ++i)
        t[ty + i * 8][tx] = W[(size_t)(k0 + ty + i * 8) * N + n0 + tx];
    __syncthreads();
    #pragma unroll
    for (int i = 0; i < 4; ++i)
        WT[(size_t)(n0 + ty + i * 8) * K + k0 + tx] = f2bf(t[tx][ty + i * 8]);
}

// 4x 768x768 weights in one launch (blockIdx.z selects)
__global__ __launch_bounds__(256) void transpose_cast4(
    const float* __restrict__ W0, const float* __restrict__ W1,
    const float* __restrict__ W2, const float* __restrict__ W3,
    ushort* __restrict__ T0, ushort* __restrict__ T1,
    ushort* __restrict__ T2, ushort* __restrict__ T3) {
    __shared__ float t[32][33];
    const int z = blockIdx.z;
    const float* W = z == 0 ? W0 : z == 1 ? W1 : z == 2 ? W2 : W3;
    ushort* WT = z == 0 ? T0 : z == 1 ? T1 : z == 2 ? T2 : T3;
    const int n0 = blockIdx.x * 32, k0 = blockIdx.y * 32;
    const int tx = threadIdx.x & 31, ty = threadIdx.x >> 5;
    #pragma unroll
    for (int i = 0; i < 4; ++i)
        t[ty + i * 8][tx] = W[(size_t)(k0 + ty + i * 8) * HDN + n0 + tx];
    __syncthreads();
    #pragma unroll
    for (int i = 0; i < 4; ++i)
        WT[(size_t)(n0 + ty + i * 8) * HDN + k0 + tx] = f2bf(t[tx][ty + i * 8]);
}

// ---------------------------------------------------------------------------
// bf16 MFMA GEMM (NT): C[M,N] = A[M,K] @ B[N,K]^T
// EPI: 0 = +bias->bf16 ; 1 = +bias+resid(f32)->f32 ;
//      2 = gelu(+bias)->bf16 ; 4 = +bias+resid(bf16)->f32
// ---------------------------------------------------------------------------
template<int EPI>
__global__ __launch_bounds__(256) void gemm_mfma(
    const ushort* __restrict__ A, const ushort* __restrict__ B,
    int lda, int ldb,
    const float* __restrict__ bias, const float* __restrict__ resid,
    const ushort* __restrict__ resid_bf,
    void* __restrict__ Cout, int M, int N, int K)
{
    __shared__ ushort As[128 * 32];
    __shared__ ushort Bs[128 * 32];

    const int tid = threadIdx.x;
    const int lane = tid & 63;
    const int wv = tid >> 6;
    const int wr = wv >> 1, wc = wv & 1;
    const int bm = blockIdx.x * 128, bn = blockIdx.y * 128;
    const int lr = lane & 15, lk = (lane >> 4) * 8;

    f32x4 acc[4][4] = {};

    for (int k0 = 0; k0 < K; k0 += 32) {
        #pragma unroll
        for (int r = 0; r < 2; ++r) {
            int slot = tid + 256 * r;
            int row = slot >> 2, q = slot & 3;
            GLOAD_LDS16(A + (size_t)(bm + row) * lda + k0 + q * 8,
                        (char*)As + slot * 16);
        }
        #pragma unroll
        for (int r = 0; r < 2; ++r) {
            int slot = tid + 256 * r;
            int row = slot >> 2, q = slot & 3;
            GLOAD_LDS16(B + (size_t)(bn + row) * ldb + k0 + q * 8,
                        (char*)Bs + slot * 16);
        }
        __syncthreads();

        short8 af[4], bfv[4];
        #pragma unroll
        for (int i = 0; i < 4; ++i) {
            af[i]  = *(const short8*)&As[(wr * 64 + i * 16 + lr) * 32 + lk];
            bfv[i] = *(const short8*)&Bs[(wc * 64 + i * 16 + lr) * 32 + lk];
        }
        #pragma unroll
        for (int i = 0; i < 4; ++i)
            #pragma unroll
            for (int j = 0; j < 4; ++j)
                acc[i][j] = __builtin_amdgcn_mfma_f32_16x16x32_bf16(
                    af[i], bfv[j], acc[i][j], 0, 0, 0);
        __syncthreads();
    }

    #pragma unroll
    for (int i = 0; i < 4; ++i) {
        #pragma unroll
        for (int j = 0; j < 4; ++j) {
            const int col = bn + wc * 64 + j * 16 + lr;
            const float bv = bias[col];
            #pragma unroll
            for (int rr = 0; rr < 4; ++rr) {
                const int row = bm + wr * 64 + i * 16 + (lane >> 4) * 4 + rr;
                const size_t idx = (size_t)row * N + col;
                float v = acc[i][j][rr] + bv;
                if (EPI == 0) {
                    ((ushort*)Cout)[idx] = f2bf(v);
                } else if (EPI == 1) {
                    ((float*)Cout)[idx] = v + resid[idx];
                } else if (EPI == 2) {
                    ((ushort*)Cout)[idx] = f2bf(geluf(v));
                } else {
                    ((float*)Cout)[idx] = v + bf2f(resid_bf[idx]);
                }
            }
        }
    }
}

// ---------------------------------------------------------------------------
// K cache (bug-faithful). kf: [bh][TKV][64] bf16. K rows come from qkv col 768+.
// ---------------------------------------------------------------------------
__global__ __launch_bounds__(256) void kvK(
    const ushort* __restrict__ qkv, const float* __restrict__ past_key,
    ushort* __restrict__ kf)
{
    const size_t total = (size_t)NBH * TKV * HDIM;
    size_t idx = (size_t)blockIdx.x * 256 + threadIdx.x;
    if (idx >= total) return;
    int d = idx & 63;
    size_t r = idx >> 6;
    int t = (int)(r % TKV);
    int bh = (int)(r / TKV);
    ushort kv_;
    if (t < LPAST) {
        kv_ = f2bf(past_key[((size_t)bh * LPAST + t) * HDIM + d]);
    } else {
        int b = bh / NHEAD, h = bh % NHEAD;
        kv_ = qkv[((size_t)(b * SEQ + (t - LPAST))) * QKVN + HDN + h * HDIM + d];
    }
    kf[idx] = kv_;
}

// ---------------------------------------------------------------------------
// V cache, transposed (bug-faithful: past_key prefix). vt: [bh][64][TKVP] bf16.
// ---------------------------------------------------------------------------
__global__ __launch_bounds__(256) void kvVT(
    const ushort* __restrict__ qkv, const float* __restrict__ past_key,
    ushort* __restrict__ vt)
{
    __shared__ ushort td[64][72];
    const int bh = blockIdx.x / 9;
    const int t0 = (blockIdx.x % 9) * 64;
    const int b = bh / NHEAD, h = bh % NHEAD;
    const int trow = threadIdx.x >> 2, seg = threadIdx.x & 3;
    const int t = t0 + trow;

    ushort vals[16];
    if (t < LPAST) {
        const float* pk = past_key + ((size_t)bh * LPAST + t) * HDIM + seg * 16;
        #pragma unroll
        for (int i = 0; i < 4; ++i) {
            float4 f = ((const float4*)pk)[i];
            vals[i * 4 + 0] = f2bf(f.x); vals[i * 4 + 1] = f2bf(f.y);
            vals[i * 4 + 2] = f2bf(f.z); vals[i * 4 + 3] = f2bf(f.w);
        }
    } else if (t < TKV) {
        const ushort* vp = qkv + ((size_t)(b * SEQ + (t - LPAST))) * QKVN
                               + 2 * HDN + h * HDIM + seg * 16;
        uint4 u0 = ((const uint4*)vp)[0], u1 = ((const uint4*)vp)[1];
        *(uint4*)&vals[0] = u0; *(uint4*)&vals[8] = u1;
    } else {
        #pragma unroll
        for (int i = 0; i < 16; ++i) vals[i] = 0;
    }
    #pragma unroll
    for (int i = 0; i < 16; ++i) td[trow][seg * 16 + i] = vals[i];
    __syncthreads();

    const int d = threadIdx.x >> 2;
    ushort o[16];
    #pragma unroll
    for (int i = 0; i < 16; ++i) o[i] = td[seg * 16 + i][d];
    ushort* dst = vt + ((size_t)bh * HDIM + d) * TKVP + t0 + seg * 16;
    *(uint4*)dst = *(uint4*)&o[0];
    *(uint4*)(dst + 8) = *(uint4*)&o[8];
}

// ---------------------------------------------------------------------------
// MFMA flash attention (as R2, Q read from fused qkv with stride QKVN).
// ---------------------------------------------------------------------------
__global__ __launch_bounds__(256) void attn3(
    const ushort* __restrict__ qkv, const ushort* __restrict__ kf,
    const ushort* __restrict__ vt, const float* __restrict__ mask,
    ushort* __restrict__ ctx)
{
    __shared__ ushort Ks[64 * 64];
    __shared__ ushort Vs[64 * 64];
    __shared__ ushort Ps[4][16 * 64];

    const int wv = threadIdx.x >> 6, lane = threadIdx.x & 63;
    const int lr = lane & 15, lg = lane >> 4;
    const int bh = blockIdx.x >> 3;
    const int s0 = (blockIdx.x & 7) * 64;
    const int b = bh / NHEAD, h = bh % NHEAD;

    short8 af[2];
    {
        const ushort* qp = qkv + ((size_t)(b * SEQ + s0 + wv * 16 + lr)) * QKVN
                               + h * HDIM + lg * 8;
        af[0] = *(const short8*)qp;
        af[1] = *(const short8*)(qp + 32);
    }

    const ushort* kbase = kf + (size_t)bh * TKV * HDIM;
    const ushort* vbase = vt + (size_t)bh * HDIM * TKVP;

    float m[4] = {-1e30f, -1e30f, -1e30f, -1e30f};
    float l[4] = {};
    f32x4 ctxa[4] = {};

    for (int kt = 0; kt < 9; ++kt) {
        const int t0 = kt * 64;
        #pragma unroll
        for (int r = 0; r < 2; ++r) {
            int sl = (int)threadIdx.x + 256 * r;
            int row = sl >> 3, p = sl & 7;
            int j = p ^ (row & 7);
            int trow = t0 + row; if (trow > TKV - 1) trow = TKV - 1;
            GLOAD_LDS16(kbase + ((size_t)trow << 6) + j * 8, (char*)Ks + sl * 16);
        }
        #pragma unroll
        for (int r = 0; r < 2; ++r) {
            int sl = (int)threadIdx.x + 256 * r;
            int row = sl >> 3, p = sl & 7;
            int j = p ^ (row & 7);
            GLOAD_LDS16(vbase + (size_t)row * TKVP + t0 + j * 8, (char*)Vs + sl * 16);
        }
        __syncthreads();

        f32x4 sa[4] = {};
        #pragma unroll
        for (int kb = 0; kb < 4; ++kb) {
            const int key = kb * 16 + lr;
            #pragma unroll
            for (int c = 0; c < 2; ++c) {
                const int phys = (c * 4 + lg) ^ (key & 7);
                short8 kfrag = *(const short8*)&Ks[key * 64 + phys * 8];
                sa[kb] = __builtin_amdgcn_mfma_f32_16x16x32_bf16(
                    af[c], kfrag, sa[kb], 0, 0, 0);
            }
        }

        float scv[4][4];
        #pragma unroll
        for (int kb = 0; kb < 4; ++kb) {
            const int t = t0 + kb * 16 + lr;
            float add = 0.0f;
            bool dead = (t >= TKV);
            if (!dead) add = (t < LPAST) ? 1.0f : mask[(size_t)b * SEQ + (t - LPAST)];
            #pragma unroll
            for (int r = 0; r < 4; ++r)
                scv[kb][r] = dead ? -1e30f : fmaf(sa[kb][r], 0.125f, add);
        }

        #pragma unroll
        for (int r = 0; r < 4; ++r) {
            float mx = fmaxf(fmaxf(scv[0][r], scv[1][r]), fmaxf(scv[2][r], scv[3][r]));
            mx = fmaxf(mx, __shfl_xor(mx, 1));
            mx = fmaxf(mx, __shfl_xor(mx, 2));
            mx = fmaxf(mx, __shfl_xor(mx, 4));
            mx = fmaxf(mx, __shfl_xor(mx, 8));
            const float mn = fmaxf(m[r], mx);
            const float f = __expf(m[r] - mn);
            m[r] = mn;
            l[r] *= f;
            #pragma unroll
            for (int dg = 0; dg < 4; ++dg) ctxa[dg][r] *= f;
            const int q_ = lg * 4 + r;
            #pragma unroll
            for (int kb = 0; kb < 4; ++kb) {
                float p = __expf(scv[kb][r] - mn);
                l[r] += p;
                const int key = kb * 16 + lr;
                const int phys = (key >> 3) ^ (q_ & 7);
                Ps[wv][q_ * 64 + phys * 8 + (key & 7)] = f2bf(p);
            }
        }

        short8 pa[2];
        #pragma unroll
        for (int c = 0; c < 2; ++c) {
            const int phys = (c * 4 + lg) ^ (lr & 7);
            pa[c] = *(const short8*)&Ps[wv][lr * 64 + phys * 8];
        }
        #pragma unroll
        for (int dg = 0; dg < 4; ++dg) {
            const int d = dg * 16 + lr;
            #pragma unroll
            for (int c = 0; c < 2; ++c) {
                const int phys = (c * 4 + lg) ^ (d & 7);
                short8 vfrag = *(const short8*)&Vs[d * 64 + phys * 8];
                ctxa[dg] = __builtin_amdgcn_mfma_f32_16x16x32_bf16(
                    pa[c], vfrag, ctxa[dg], 0, 0, 0);
            }
        }
        __syncthreads();
    }

    #pragma unroll
    for (int r = 0; r < 4; ++r) {
        float s = l[r];
        s += __shfl_xor(s, 1); s += __shfl_xor(s, 2);
        s += __shfl_xor(s, 4); s += __shfl_xor(s, 8);
        l[r] = 1.0f / s;
    }
    #pragma unroll
    for (int r = 0; r < 4; ++r) {
        const int q_ = s0 + wv * 16 + lg * 4 + r;
        const size_t base = ((size_t)(b * SEQ + q_)) * HDN + h * HDIM;
        #pragma unroll
        for (int dg = 0; dg < 4; ++dg)
            ctx[base + dg * 16 + lr] = f2bf(ctxa[dg][r] * l[r]);
    }
}

// ---------------------------------------------------------------------------
// LayerNorm(768); f32 out and/or bf16 out (either may be null).
// ---------------------------------------------------------------------------
__global__ __launch_bounds__(256) void layernorm2(
    const float* __restrict__ x, const float* __restrict__ g,
    const float* __restrict__ b, float* __restrict__ out,
    ushort* __restrict__ out_bf)
{
    const size_t row = blockIdx.x;
    const float* xr = &x[row * HDN];
    const int t = threadIdx.x;

    float v0 = xr[t], v1 = xr[t + 256], v2 = xr[t + 512];

    __shared__ float red[4];
    float s = v0 + v1 + v2;
    #pragma unroll
    for (int off = 32; off > 0; off >>= 1) s += __shfl_xor(s, off);
    if ((t & 63) == 0) red[t >> 6] = s;
    __syncthreads();
    float mean = (red[0] + red[1] + red[2] + red[3]) * (1.0f / 768.0f);

    float d0 = v0 - mean, d1 = v1 - mean, d2 = v2 - mean;
    float vs = d0 * d0 + d1 * d1 + d2 * d2;
    #pragma unroll
    for (int off = 32; off > 0; off >>= 1) vs += __shfl_xor(vs, off);
    __syncthreads();
    if ((t & 63) == 0) red[t >> 6] = vs;
    __syncthreads();
    float var = (red[0] + red[1] + red[2] + red[3]) * (1.0f / 768.0f);
    float rstd = rsqrtf(var + 1e-12f);

    float o0 = d0 * rstd * g[t] + b[t];
    float o1 = d1 * rstd * g[t + 256] + b[t + 256];
    float o2 = d2 * rstd * g[t + 512] + b[t + 512];
    if (out) {
        out[row * HDN + t] = o0;
        out[row * HDN + t + 256] = o1;
        out[row * HDN + t + 512] = o2;
    }
    if (out_bf) {
        out_bf[row * HDN + t] = f2bf(o0);
        out_bf[row * HDN + t + 256] = f2bf(o1);
        out_bf[row * HDN + t + 512] = f2bf(o2);
    }
}

// ---------------------------------------------------------------------------
extern "C" void kernel_launch(void* const* d_in, const int* in_sizes, int n_in,
                              void* d_out, int out_size, void* d_ws, size_t ws_size,
                              hipStream_t stream) {
    const float* hs       = (const float*)d_in[0];
    const float* mask     = (const float*)d_in[1];
    const float* past_key = (const float*)d_in[2];
    const float* Wq = (const float*)d_in[4];
    const float* bq = (const float*)d_in[5];
    const float* Wk = (const float*)d_in[6];
    const float* bk = (const float*)d_in[7];
    const float* Wv = (const float*)d_in[8];
    const float* bv = (const float*)d_in[9];
    const float* Wo = (const float*)d_in[10];
    const float* bo = (const float*)d_in[11];
    const float* ln1_g = (const float*)d_in[12];
    const float* ln1_b = (const float*)d_in[13];
    const float* Wi = (const float*)d_in[14];
    const float* bi = (const float*)d_in[15];
    const float* Wf = (const float*)d_in[16];
    const float* bf_ = (const float*)d_in[17];
    const float* ln2_g = (const float*)d_in[18];
    const float* ln2_b = (const float*)d_in[19];
    float* out = (float*)d_out;

    char* w = (char*)d_ws;
    // persistent weights: 0 .. 14,155,776
    ushort* WqT   = (ushort*)(w + 0);          // [2304][768] fused (Wq,Wk,Wv contiguous)
    ushort* WoT   = (ushort*)(w + 3538944);
    ushort* WiT   = (ushort*)(w + 4718592);    // [3072][768]
    ushort* WfT   = (ushort*)(w + 9437184);    // [768][3072]
    float*  bqkv  = (float*)(w + 14155776);    // 9216 B (padded to 16384)
    ushort* hs_bf = (ushort*)(w + 14172160);   // 12.6 MB, dead after QKV
    ushort* qkv   = (ushort*)(w + 26755072);   // [8192][2304] 37.7 MB, dead after attn
    ushort* kf    = (ushort*)(w + 64503808);   // 13.8 MB, dead after attn
    ushort* vt    = (ushort*)(w + 78315520);   // 14.2 MB, dead after attn
    ushort* ctx_bf = hs_bf;                    // overlays hs_bf (dead after QKV)
    float*  tmp   = (float*)(w + 64503808);    // 25.2 MB over kf+vt (dead post-attn)
    ushort* inter = (ushort*)(w + 14172160);   // [8192][3072] 50.3 MB over hs/ctx/qkv
    ushort* aln_bf = (ushort*)(w + 89669632);  // 12.6 MB -> ends 102,252,544
    ushort* WkT = WqT + (size_t)HDN * HDN;
    ushort* WvT = WqT + (size_t)2 * HDN * HDN;

    dim3 b256(256);

    cast_bf<<<dim3((MTOK * HDN / 4 + 255) / 256), b256, 0, stream>>>(hs, hs_bf, MTOK * HDN / 4);
    pack_bias<<<dim3(9), b256, 0, stream>>>(bq, bk, bv, bqkv);
    transpose_cast4<<<dim3(24, 24, 4), b256, 0, stream>>>(Wq, Wk, Wv, Wo, WqT, WkT, WvT, WoT);
    transpose_cast<<<dim3(96, 24), b256, 0, stream>>>(Wi, WiT, HDN, FFDIM);
    transpose_cast<<<dim3(24, 96), b256, 0, stream>>>(Wf, WfT, FFDIM, HDN);

    // fused QKV: [8192,768] @ [2304,768]^T -> qkv bf16
    gemm_mfma<0><<<dim3(MTOK / 128, QKVN / 128), b256, 0, stream>>>(
        hs_bf, WqT, HDN, HDN, bqkv, nullptr, nullptr, qkv, MTOK, QKVN, HDN);

    {
        size_t ktot = (size_t)NBH * TKV * HDIM;
        kvK<<<dim3((unsigned)((ktot + 255) / 256)), b256, 0, stream>>>(qkv, past_key, kf);
    }
    kvVT<<<dim3(NBH * 9), b256, 0, stream>>>(qkv, past_key, vt);

    attn3<<<dim3(NBH * 8), b256, 0, stream>>>(qkv, kf, vt, mask, ctx_bf);

    // Wo + residual(hs f32) -> tmp f32 ; LN1 -> bf16 only
    gemm_mfma<1><<<dim3(MTOK / 128, HDN / 128), b256, 0, stream>>>(
        ctx_bf, WoT, HDN, HDN, bo, hs, nullptr, tmp, MTOK, HDN, HDN);
    layernorm2<<<dim3(MTOK), b256, 0, stream>>>(tmp, ln1_g, ln1_b, nullptr, aln_bf);

    // FFN full width: Wi (N=3072, gelu) -> inter ; Wf (K=3072, +bf16 resid) -> tmp
    gemm_mfma<2><<<dim3(MTOK / 128, FFDIM / 128), b256, 0, stream>>>(
        aln_bf, WiT, HDN, HDN, bi, nullptr, nullptr, inter, MTOK, FFDIM, HDN);
    gemm_mfma<4><<<dim3(MTOK / 128, HDN / 128), b256, 0, stream>>>(
        inter, WfT, FFDIM, FFDIM, bf_, nullptr, aln_bf, tmp, MTOK, HDN, FFDIM);

    layernorm2<<<dim3(MTOK), b256, 0, stream>>>(tmp, ln2_g, ln2_b, out, nullptr);
}

// Round 5
// 275.098 us; speedup vs baseline: 18.1488x; 1.1983x over previous
//
#include <hip/hip_runtime.h>
#include <math.h>

#define HDIM 64
#define NHEAD 12
#define HDN 768
#define QKVN 2304
#define FFDIM 3072
#define LPAST 50
#define SEQ 512
#define NBATCH 16
#define TKV (LPAST + SEQ)     // 562
#define TKVP 576
#define MTOK (NBATCH * SEQ)   // 8192
#define NBH (NBATCH * NHEAD)  // 192

typedef __attribute__((ext_vector_type(8))) short short8;
typedef __attribute__((ext_vector_type(4))) float f32x4;

__device__ __forceinline__ ushort f2bf(float x) {
    union { float f; unsigned u; } c; c.f = x;
    unsigned r = (c.u + 0x7fffu + ((c.u >> 16) & 1u)) >> 16;
    return (ushort)r;
}
__device__ __forceinline__ float bf2f(ushort u) { return __uint_as_float((unsigned)u << 16); }
__device__ __forceinline__ float geluf(float v) {
    return 0.5f * v * (1.0f + erff(v * 0.70710678118654752f));
}

#define GLOAD_LDS16(gsrc, ldst)                                                    \
    __builtin_amdgcn_global_load_lds(                                              \
        (const __attribute__((address_space(1))) void*)(gsrc),                     \
        (__attribute__((address_space(3))) void*)(ldst), 16, 0, 0)

// ---------------------------------------------------------------------------
__global__ __launch_bounds__(256) void cast_bf(const float* __restrict__ x,
                                               ushort* __restrict__ y, int n4) {
    int i = blockIdx.x * 256 + threadIdx.x;
    if (i >= n4) return;
    float4 v = ((const float4*)x)[i];
    ushort4 o; o.x = f2bf(v.x); o.y = f2bf(v.y); o.z = f2bf(v.z); o.w = f2bf(v.w);
    ((ushort4*)y)[i] = o;
}

__global__ __launch_bounds__(256) void pack_bias(const float* __restrict__ bq,
                                                 const float* __restrict__ bk,
                                                 const float* __restrict__ bv,
                                                 float* __restrict__ o) {
    int i = blockIdx.x * 256 + threadIdx.x;
    if (i >= QKVN) return;
    o[i] = i < HDN ? bq[i] : (i < 2 * HDN ? bk[i - HDN] : bv[i - 2 * HDN]);
}

// ---------------------------------------------------------------------------
// W[K][N] fp32 -> WT[N][K] bf16
// ---------------------------------------------------------------------------
__global__ __launch_bounds__(256) void transpose_cast(const float* __restrict__ W,
                                                      ushort* __restrict__ WT,
                                                      int K, int N) {
    __shared__ float t[32][33];
    const int n0 = blockIdx.x * 32, k0 = blockIdx.y * 32;
    const int tx = threadIdx.x & 31, ty = threadIdx.x >> 5;
    #pragma unroll
    for (int i = 0; i < 4; ++i)
        t[ty + i * 8][tx] = W[(size_t)(k0 + ty + i * 8) * N + n0 + tx];
    __syncthreads();
    #pragma unroll
    for (int i = 0; i < 4; ++i)
        WT[(size_t)(n0 + ty + i * 8) * K + k0 + tx] = f2bf(t[tx][ty + i * 8]);
}

__global__ __launch_bounds__(256) void transpose_cast4(
    const float* __restrict__ W0, const float* __restrict__ W1,
    const float* __restrict__ W2, const float* __restrict__ W3,
    ushort* __restrict__ T0, ushort* __restrict__ T1,
    ushort* __restrict__ T2, ushort* __restrict__ T3) {
    __shared__ float t[32][33];
    const int z = blockIdx.z;
    const float* W = z == 0 ? W0 : z == 1 ? W1 : z == 2 ? W2 : W3;
    ushort* WT = z == 0 ? T0 : z == 1 ? T1 : z == 2 ? T2 : T3;
    const int n0 = blockIdx.x * 32, k0 = blockIdx.y * 32;
    const int tx = threadIdx.x & 31, ty = threadIdx.x >> 5;
    #pragma unroll
    for (int i = 0; i < 4; ++i)
        t[ty + i * 8][tx] = W[(size_t)(k0 + ty + i * 8) * HDN + n0 + tx];
    __syncthreads();
    #pragma unroll
    for (int i = 0; i < 4; ++i)
        WT[(size_t)(n0 + ty + i * 8) * HDN + k0 + tx] = f2bf(t[tx][ty + i * 8]);
}

// ---------------------------------------------------------------------------
// bf16 MFMA GEMM (NT): C[M,N] = A[M,K] @ B[N,K]^T
// 128x128 tile, BK=32, 4 waves (2x2), 3-buffer LDS rotation, counted vmcnt,
// st_16x32-swizzled subtiled LDS (16x32 bf16 = 1024B subtiles,
// byte ^= ((byte>>9)&1)<<5), staged linear via global_load_lds from
// inverse-swizzled global source.  Raw s_barrier (no vmcnt(0) drain).
// EPI: 0 = +bias->bf16 ; 1 = +bias+resid(f32)->f32 ;
//      2 = gelu(+bias)->bf16 ; 4 = +bias+resid(bf16)->f32
// ---------------------------------------------------------------------------
template<int EPI>
__global__ __launch_bounds__(256) void gemm_mfma3(
    const ushort* __restrict__ A, const ushort* __restrict__ B,
    int lda, int ldb,
    const float* __restrict__ bias, const float* __restrict__ resid,
    const ushort* __restrict__ resid_bf,
    void* __restrict__ Cout, int M, int N, int K)
{
    __shared__ ushort sm[3 * 8192];   // 3 bufs x (A 8KB + B 8KB)

    const int tid = threadIdx.x;
    const int lane = tid & 63;
    const int wv = tid >> 6;
    const int wr = wv >> 1, wc = wv & 1;
    const int bm = blockIdx.x * 128, bn = blockIdx.y * 128;
    const int lr = lane & 15, lg = lane >> 4;
    // fragment read byte offset within a subtile (swizzled), in ushorts
    const int swzu = ((lr * 64 + lg * 16) ^ ((lr & 8) << 2)) >> 1;

    // staging decode: slot sl (16B) -> logical (row, k) s.t. LDS-linear write +
    // swizzled read agree.  o=sl*16; subtile=o>>10; q=o&1023; q^=((q>>9)&1)<<5;
    // row=subtile*16 + q>>6 ; k=(q&63)>>1
    int srow[2], skk[2];
    #pragma unroll
    for (int r = 0; r < 2; ++r) {
        int o = (tid + 256 * r) * 16;
        int st = o >> 10;
        int q = o & 1023;
        q ^= ((q >> 9) & 1) << 5;
        srow[r] = st * 16 + (q >> 6);
        skk[r] = (q & 63) >> 1;
    }
    const ushort* Abase = A + (size_t)bm * lda;
    const ushort* Bbase = B + (size_t)bn * ldb;
    const int nt = K >> 5;

    f32x4 acc[4][4] = {};

#define STAGE(T, BUF)                                                            \
    do {                                                                         \
        const int k0_ = (T) << 5;                                                \
        ushort* base_ = sm + (BUF) * 8192;                                       \
        _Pragma("unroll")                                                        \
        for (int r_ = 0; r_ < 2; ++r_) {                                         \
            int sl_ = tid + 256 * r_;                                            \
            GLOAD_LDS16(Abase + (size_t)srow[r_] * lda + k0_ + skk[r_],          \
                        (char*)base_ + sl_ * 16);                                \
        }                                                                        \
        _Pragma("unroll")                                                        \
        for (int r_ = 0; r_ < 2; ++r_) {                                         \
            int sl_ = tid + 256 * r_;                                            \
            GLOAD_LDS16(Bbase + (size_t)srow[r_] * ldb + k0_ + skk[r_],          \
                        (char*)(base_ + 4096) + sl_ * 16);                       \
        }                                                                        \
    } while (0)

    STAGE(0, 0);
    STAGE(1, 1);
    asm volatile("s_waitcnt vmcnt(4)" ::: "memory");
    __builtin_amdgcn_sched_barrier(0);
    __builtin_amdgcn_s_barrier();
    __builtin_amdgcn_sched_barrier(0);

    int buf = 0;
    for (int t = 0; t < nt; ++t) {
        if (t + 2 < nt) {
            int nbuf = buf + 2; if (nbuf >= 3) nbuf -= 3;
            STAGE(t + 2, nbuf);
        }
        const ushort* ab = sm + buf * 8192;
        short8 af[4], bfv[4];
        #pragma unroll
        for (int i = 0; i < 4; ++i) {
            af[i]  = *(const short8*)(ab + (wr * 4 + i) * 512 + swzu);
            bfv[i] = *(const short8*)(ab + 4096 + (wc * 4 + i) * 512 + swzu);
        }
        __builtin_amdgcn_s_setprio(1);
        #pragma unroll
        for (int i = 0; i < 4; ++i)
            #pragma unroll
            for (int j = 0; j < 4; ++j)
                acc[i][j] = __builtin_amdgcn_mfma_f32_16x16x32_bf16(
                    af[i], bfv[j], acc[i][j], 0, 0, 0);
        __builtin_amdgcn_s_setprio(0);
        if (t + 2 < nt)
            asm volatile("s_waitcnt vmcnt(4)" ::: "memory");
        else
            asm volatile("s_waitcnt vmcnt(0)" ::: "memory");
        __builtin_amdgcn_sched_barrier(0);
        __builtin_amdgcn_s_barrier();
        __builtin_amdgcn_sched_barrier(0);
        buf = buf + 1 == 3 ? 0 : buf + 1;
    }
#undef STAGE

    #pragma unroll
    for (int i = 0; i < 4; ++i) {
        #pragma unroll
        for (int j = 0; j < 4; ++j) {
            const int col = bn + wc * 64 + j * 16 + lr;
            const float bv = bias[col];
            #pragma unroll
            for (int rr = 0; rr < 4; ++rr) {
                const int row = bm + wr * 64 + i * 16 + (lane >> 4) * 4 + rr;
                const size_t idx = (size_t)row * N + col;
                float v = acc[i][j][rr] + bv;
                if (EPI == 0) {
                    ((ushort*)Cout)[idx] = f2bf(v);
                } else if (EPI == 1) {
                    ((float*)Cout)[idx] = v + resid[idx];
                } else if (EPI == 2) {
                    ((ushort*)Cout)[idx] = f2bf(geluf(v));
                } else {
                    ((float*)Cout)[idx] = v + bf2f(resid_bf[idx]);
                }
            }
        }
    }
}

// ---------------------------------------------------------------------------
// K cache (bug-faithful). kf: [bh][TKV][64] bf16. K rows come from qkv col 768+.
// ---------------------------------------------------------------------------
__global__ __launch_bounds__(256) void kvK(
    const ushort* __restrict__ qkv, const float* __restrict__ past_key,
    ushort* __restrict__ kf)
{
    const size_t total = (size_t)NBH * TKV * HDIM;
    size_t idx = (size_t)blockIdx.x * 256 + threadIdx.x;
    if (idx >= total) return;
    int d = idx & 63;
    size_t r = idx >> 6;
    int t = (int)(r % TKV);
    int bh = (int)(r / TKV);
    ushort kv_;
    if (t < LPAST) {
        kv_ = f2bf(past_key[((size_t)bh * LPAST + t) * HDIM + d]);
    } else {
        int b = bh / NHEAD, h = bh % NHEAD;
        kv_ = qkv[((size_t)(b * SEQ + (t - LPAST))) * QKVN + HDN + h * HDIM + d];
    }
    kf[idx] = kv_;
}

// ---------------------------------------------------------------------------
// V cache, transposed (bug-faithful: past_key prefix). vt: [bh][64][TKVP] bf16.
// ---------------------------------------------------------------------------
__global__ __launch_bounds__(256) void kvVT(
    const ushort* __restrict__ qkv, const float* __restrict__ past_key,
    ushort* __restrict__ vt)
{
    __shared__ ushort td[64][72];
    const int bh = blockIdx.x / 9;
    const int t0 = (blockIdx.x % 9) * 64;
    const int b = bh / NHEAD, h = bh % NHEAD;
    const int trow = threadIdx.x >> 2, seg = threadIdx.x & 3;
    const int t = t0 + trow;

    ushort vals[16];
    if (t < LPAST) {
        const float* pk = past_key + ((size_t)bh * LPAST + t) * HDIM + seg * 16;
        #pragma unroll
        for (int i = 0; i < 4; ++i) {
            float4 f = ((const float4*)pk)[i];
            vals[i * 4 + 0] = f2bf(f.x); vals[i * 4 + 1] = f2bf(f.y);
            vals[i * 4 + 2] = f2bf(f.z); vals[i * 4 + 3] = f2bf(f.w);
        }
    } else if (t < TKV) {
        const ushort* vp = qkv + ((size_t)(b * SEQ + (t - LPAST))) * QKVN
                               + 2 * HDN + h * HDIM + seg * 16;
        uint4 u0 = ((const uint4*)vp)[0], u1 = ((const uint4*)vp)[1];
        *(uint4*)&vals[0] = u0; *(uint4*)&vals[8] = u1;
    } else {
        #pragma unroll
        for (int i = 0; i < 16; ++i) vals[i] = 0;
    }
    #pragma unroll
    for (int i = 0; i < 16; ++i) td[trow][seg * 16 + i] = vals[i];
    __syncthreads();

    const int d = threadIdx.x >> 2;
    ushort o[16];
    #pragma unroll
    for (int i = 0; i < 16; ++i) o[i] = td[seg * 16 + i][d];
    ushort* dst = vt + ((size_t)bh * HDIM + d) * TKVP + t0 + seg * 16;
    *(uint4*)dst = *(uint4*)&o[0];
    *(uint4*)(dst + 8) = *(uint4*)&o[8];
}

// ---------------------------------------------------------------------------
// MFMA flash attention.  XCD-grouped blockIdx remap: the 8 q-blocks of one
// (b,h) land on one XCD so K/V stay L2-resident (xcd = bid & 7).
// ---------------------------------------------------------------------------
__global__ __launch_bounds__(256) void attn3(
    const ushort* __restrict__ qkv, const ushort* __restrict__ kf,
    const ushort* __restrict__ vt, const float* __restrict__ mask,
    ushort* __restrict__ ctx)
{
    __shared__ ushort Ks[64 * 64];
    __shared__ ushort Vs[64 * 64];
    __shared__ ushort Ps[4][16 * 64];

    const int wv = threadIdx.x >> 6, lane = threadIdx.x & 63;
    const int lr = lane & 15, lg = lane >> 4;
    const int bid = blockIdx.x;
    const int xcd = bid & 7, gi = bid >> 3;
    const int bh = xcd * (NBH / 8) + (gi >> 3);
    const int s0 = (gi & 7) * 64;
    const int b = bh / NHEAD, h = bh % NHEAD;

    short8 af[2];
    {
        const ushort* qp = qkv + ((size_t)(b * SEQ + s0 + wv * 16 + lr)) * QKVN
                               + h * HDIM + lg * 8;
        af[0] = *(const short8*)qp;
        af[1] = *(const short8*)(qp + 32);
    }

    const ushort* kbase = kf + (size_t)bh * TKV * HDIM;
    const ushort* vbase = vt + (size_t)bh * HDIM * TKVP;

    float m[4] = {-1e30f, -1e30f, -1e30f, -1e30f};
    float l[4] = {};
    f32x4 ctxa[4] = {};

    for (int kt = 0; kt < 9; ++kt) {
        const int t0 = kt * 64;
        #pragma unroll
        for (int r = 0; r < 2; ++r) {
            int sl = (int)threadIdx.x + 256 * r;
            int row = sl >> 3, p = sl & 7;
            int j = p ^ (row & 7);
            int trow = t0 + row; if (trow > TKV - 1) trow = TKV - 1;
            GLOAD_LDS16(kbase + ((size_t)trow << 6) + j * 8, (char*)Ks + sl * 16);
        }
        #pragma unroll
        for (int r = 0; r < 2; ++r) {
            int sl = (int)threadIdx.x + 256 * r;
            int row = sl >> 3, p = sl & 7;
            int j = p ^ (row & 7);
            GLOAD_LDS16(vbase + (size_t)row * TKVP + t0 + j * 8, (char*)Vs + sl * 16);
        }
        __syncthreads();

        f32x4 sa[4] = {};
        #pragma unroll
        for (int kb = 0; kb < 4; ++kb) {
            const int key = kb * 16 + lr;
            #pragma unroll
            for (int c = 0; c < 2; ++c) {
                const int phys = (c * 4 + lg) ^ (key & 7);
                short8 kfrag = *(const short8*)&Ks[key * 64 + phys * 8];
                sa[kb] = __builtin_amdgcn_mfma_f32_16x16x32_bf16(
                    af[c], kfrag, sa[kb], 0, 0, 0);
            }
        }

        float scv[4][4];
        #pragma unroll
        for (int kb = 0; kb < 4; ++kb) {
            const int t = t0 + kb * 16 + lr;
            float add = 0.0f;
            bool dead = (t >= TKV);
            if (!dead) add = (t < LPAST) ? 1.0f : mask[(size_t)b * SEQ + (t - LPAST)];
            #pragma unroll
            for (int r = 0; r < 4; ++r)
                scv[kb][r] = dead ? -1e30f : fmaf(sa[kb][r], 0.125f, add);
        }

        #pragma unroll
        for (int r = 0; r < 4; ++r) {
            float mx = fmaxf(fmaxf(scv[0][r], scv[1][r]), fmaxf(scv[2][r], scv[3][r]));
            mx = fmaxf(mx, __shfl_xor(mx, 1));
            mx = fmaxf(mx, __shfl_xor(mx, 2));
            mx = fmaxf(mx, __shfl_xor(mx, 4));
            mx = fmaxf(mx, __shfl_xor(mx, 8));
            const float mn = fmaxf(m[r], mx);
            const float f = __expf(m[r] - mn);
            m[r] = mn;
            l[r] *= f;
            #pragma unroll
            for (int dg = 0; dg < 4; ++dg) ctxa[dg][r] *= f;
            const int q_ = lg * 4 + r;
            #pragma unroll
            for (int kb = 0; kb < 4; ++kb) {
                float p = __expf(scv[kb][r] - mn);
                l[r] += p;
                const int key = kb * 16 + lr;
                const int phys = (key >> 3) ^ (q_ & 7);
                Ps[wv][q_ * 64 + phys * 8 + (key & 7)] = f2bf(p);
            }
        }

        short8 pa[2];
        #pragma unroll
        for (int c = 0; c < 2; ++c) {
            const int phys = (c * 4 + lg) ^ (lr & 7);
            pa[c] = *(const short8*)&Ps[wv][lr * 64 + phys * 8];
        }
        #pragma unroll
        for (int dg = 0; dg < 4; ++dg) {
            const int d = dg * 16 + lr;
            #pragma unroll
            for (int c = 0; c < 2; ++c) {
                const int phys = (c * 4 + lg) ^ (d & 7);
                short8 vfrag = *(const short8*)&Vs[d * 64 + phys * 8];
                ctxa[dg] = __builtin_amdgcn_mfma_f32_16x16x32_bf16(
                    pa[c], vfrag, ctxa[dg], 0, 0, 0);
            }
        }
        __syncthreads();
    }

    #pragma unroll
    for (int r = 0; r < 4; ++r) {
        float s = l[r];
        s += __shfl_xor(s, 1); s += __shfl_xor(s, 2);
        s += __shfl_xor(s, 4); s += __shfl_xor(s, 8);
        l[r] = 1.0f / s;
    }
    #pragma unroll
    for (int r = 0; r < 4; ++r) {
        const int q_ = s0 + wv * 16 + lg * 4 + r;
        const size_t base = ((size_t)(b * SEQ + q_)) * HDN + h * HDIM;
        #pragma unroll
        for (int dg = 0; dg < 4; ++dg)
            ctx[base + dg * 16 + lr] = f2bf(ctxa[dg][r] * l[r]);
    }
}

// ---------------------------------------------------------------------------
// LayerNorm(768); f32 out and/or bf16 out (either may be null).
// ---------------------------------------------------------------------------
__global__ __launch_bounds__(256) void layernorm2(
    const float* __restrict__ x, const float* __restrict__ g,
    const float* __restrict__ b, float* __restrict__ out,
    ushort* __restrict__ out_bf)
{
    const size_t row = blockIdx.x;
    const float* xr = &x[row * HDN];
    const int t = threadIdx.x;

    float v0 = xr[t], v1 = xr[t + 256], v2 = xr[t + 512];

    __shared__ float red[4];
    float s = v0 + v1 + v2;
    #pragma unroll
    for (int off = 32; off > 0; off >>= 1) s += __shfl_xor(s, off);
    if ((t & 63) == 0) red[t >> 6] = s;
    __syncthreads();
    float mean = (red[0] + red[1] + red[2] + red[3]) * (1.0f / 768.0f);

    float d0 = v0 - mean, d1 = v1 - mean, d2 = v2 - mean;
    float vs = d0 * d0 + d1 * d1 + d2 * d2;
    #pragma unroll
    for (int off = 32; off > 0; off >>= 1) vs += __shfl_xor(vs, off);
    __syncthreads();
    if ((t & 63) == 0) red[t >> 6] = vs;
    __syncthreads();
    float var = (red[0] + red[1] + red[2] + red[3]) * (1.0f / 768.0f);
    float rstd = rsqrtf(var + 1e-12f);

    float o0 = d0 * rstd * g[t] + b[t];
    float o1 = d1 * rstd * g[t + 256] + b[t + 256];
    float o2 = d2 * rstd * g[t + 512] + b[t + 512];
    if (out) {
        out[row * HDN + t] = o0;
        out[row * HDN + t + 256] = o1;
        out[row * HDN + t + 512] = o2;
    }
    if (out_bf) {
        out_bf[row * HDN + t] = f2bf(o0);
        out_bf[row * HDN + t + 256] = f2bf(o1);
        out_bf[row * HDN + t + 512] = f2bf(o2);
    }
}

// ---------------------------------------------------------------------------
extern "C" void kernel_launch(void* const* d_in, const int* in_sizes, int n_in,
                              void* d_out, int out_size, void* d_ws, size_t ws_size,
                              hipStream_t stream) {
    const float* hs       = (const float*)d_in[0];
    const float* mask     = (const float*)d_in[1];
    const float* past_key = (const float*)d_in[2];
    const float* Wq = (const float*)d_in[4];
    const float* bq = (const float*)d_in[5];
    const float* Wk = (const float*)d_in[6];
    const float* bk = (const float*)d_in[7];
    const float* Wv = (const float*)d_in[8];
    const float* bv = (const float*)d_in[9];
    const float* Wo = (const float*)d_in[10];
    const float* bo = (const float*)d_in[11];
    const float* ln1_g = (const float*)d_in[12];
    const float* ln1_b = (const float*)d_in[13];
    const float* Wi = (const float*)d_in[14];
    const float* bi = (const float*)d_in[15];
    const float* Wf = (const float*)d_in[16];
    const float* bf_ = (const float*)d_in[17];
    const float* ln2_g = (const float*)d_in[18];
    const float* ln2_b = (const float*)d_in[19];
    float* out = (float*)d_out;

    char* w = (char*)d_ws;
    ushort* WqT   = (ushort*)(w + 0);          // [2304][768] fused
    ushort* WoT   = (ushort*)(w + 3538944);
    ushort* WiT   = (ushort*)(w + 4718592);    // [3072][768]
    ushort* WfT   = (ushort*)(w + 9437184);    // [768][3072]
    float*  bqkv  = (float*)(w + 14155776);
    ushort* hs_bf = (ushort*)(w + 14172160);
    ushort* qkv   = (ushort*)(w + 26755072);
    ushort* kf    = (ushort*)(w + 64503808);
    ushort* vt    = (ushort*)(w + 78315520);
    ushort* ctx_bf = hs_bf;
    float*  tmp   = (float*)(w + 64503808);
    ushort* inter = (ushort*)(w + 14172160);
    ushort* aln_bf = (ushort*)(w + 89669632);
    ushort* WkT = WqT + (size_t)HDN * HDN;
    ushort* WvT = WqT + (size_t)2 * HDN * HDN;

    dim3 b256(256);

    cast_bf<<<dim3((MTOK * HDN / 4 + 255) / 256), b256, 0, stream>>>(hs, hs_bf, MTOK * HDN / 4);
    pack_bias<<<dim3(9), b256, 0, stream>>>(bq, bk, bv, bqkv);
    transpose_cast4<<<dim3(24, 24, 4), b256, 0, stream>>>(Wq, Wk, Wv, Wo, WqT, WkT, WvT, WoT);
    transpose_cast<<<dim3(96, 24), b256, 0, stream>>>(Wi, WiT, HDN, FFDIM);
    transpose_cast<<<dim3(24, 96), b256, 0, stream>>>(Wf, WfT, FFDIM, HDN);

    // fused QKV
    gemm_mfma3<0><<<dim3(MTOK / 128, QKVN / 128), b256, 0, stream>>>(
        hs_bf, WqT, HDN, HDN, bqkv, nullptr, nullptr, qkv, MTOK, QKVN, HDN);

    {
        size_t ktot = (size_t)NBH * TKV * HDIM;
        kvK<<<dim3((unsigned)((ktot + 255) / 256)), b256, 0, stream>>>(qkv, past_key, kf);
    }
    kvVT<<<dim3(NBH * 9), b256, 0, stream>>>(qkv, past_key, vt);

    attn3<<<dim3(NBH * 8), b256, 0, stream>>>(qkv, kf, vt, mask, ctx_bf);

    // Wo + residual(hs f32) -> tmp f32 ; LN1 -> bf16 only
    gemm_mfma3<1><<<dim3(MTOK / 128, HDN / 128), b256, 0, stream>>>(
        ctx_bf, WoT, HDN, HDN, bo, hs, nullptr, tmp, MTOK, HDN, HDN);
    layernorm2<<<dim3(MTOK), b256, 0, stream>>>(tmp, ln1_g, ln1_b, nullptr, aln_bf);

    // FFN full width
    gemm_mfma3<2><<<dim3(MTOK / 128, FFDIM / 128), b256, 0, stream>>>(
        aln_bf, WiT, HDN, HDN, bi, nullptr, nullptr, inter, MTOK, FFDIM, HDN);
    gemm_mfma3<4><<<dim3(MTOK / 128, HDN / 128), b256, 0, stream>>>(
        inter, WfT, FFDIM, FFDIM, bf_, nullptr, aln_bf, tmp, MTOK, HDN, FFDIM);

    layernorm2<<<dim3(MTOK), b256, 0, stream>>>(tmp, ln2_g, ln2_b, out, nullptr);
}